// Round 8
// baseline (456.248 us; speedup 1.0000x reference)
//
#include <hip/hip_runtime.h>
#include <hip/hip_bf16.h>

typedef unsigned short u16;
typedef unsigned int u32;
typedef __bf16 v8bf __attribute__((ext_vector_type(8)));
typedef float v4f __attribute__((ext_vector_type(4)));

#define B_SZ 8
#define S_LEN 1024
#define IN_DIM 256
#define DMODEL 512
#define NHEAD 8
#define DK 64
#define FF_DIM 2048
#define MROWS (B_SZ * S_LEN)   // 8192
#define QSCALE 0.1803368801111204f   // 0.125 * log2(e)

__device__ __forceinline__ u16 f2bf(float f) {
    unsigned int x = __float_as_uint(f);
    unsigned int r = (x + 0x7fffu + ((x >> 16) & 1u)) >> 16;
    return (u16)r;
}

// async global->LDS DMA, 16B per lane; lds dest is wave-uniform base + lane*16
__device__ __forceinline__ void gl16(const u16* g, u16* l) {
    __builtin_amdgcn_global_load_lds((const __attribute__((address_space(1))) unsigned int*)g,
                                     (__attribute__((address_space(3))) unsigned int*)l, 16, 0, 0);
}

// ---------------- elementwise f32 -> bf16 (inputs matrix) ----------------
__global__ __launch_bounds__(256) void conv_bf16_kernel(const float* __restrict__ in,
                                                        u16* __restrict__ out, int n4) {
    int i = blockIdx.x * 256 + threadIdx.x;
    if (i < n4) {
        float4 v = ((const float4*)in)[i];
        ushort4 o;
        o.x = f2bf(v.x); o.y = f2bf(v.y); o.z = f2bf(v.z); o.w = f2bf(v.w);
        ((ushort4*)out)[i] = o;
    }
}

// ------------- batched transpose+convert: (K,N) f32 -> (N,K) bf16 -------------
// exact tiling: flattened 1-D grid, host-computed per-desc tile offsets (no no-op blocks).
struct TDesc { const float* src; u16* dst; int K; int N; };
struct TArgs { TDesc d[13]; int start[14]; int l2tn[13]; };

__global__ void transpose_conv_kernel(TArgs args) {
    int bid = blockIdx.x;
    int z = 0;
    while (z < 12 && bid >= args.start[z + 1]) z++;
    TDesc t = args.d[z];
    int local = bid - args.start[z];
    int l2 = args.l2tn[z];
    int k0 = (local >> l2) << 5;
    int n0 = (local & ((1 << l2) - 1)) << 5;
    __shared__ float tile[32][33];
    int tx = threadIdx.x, ty = threadIdx.y;
#pragma unroll
    for (int j = 0; j < 4; j++) {
        int k = k0 + ty + j * 8;
        tile[ty + j * 8][tx] = t.src[(size_t)k * t.N + n0 + tx];
    }
    __syncthreads();
#pragma unroll
    for (int j = 0; j < 4; j++) {
        int n = n0 + ty + j * 8;
        t.dst[(size_t)n * t.K + k0 + tx] = f2bf(tile[tx][ty + j * 8]);
    }
}

// ---------------- LayerNorm: fp32 in -> bf16 (or fp32) out ----------------
template <bool OUT_BF16>
__global__ __launch_bounds__(256) void ln_kernel(const float* __restrict__ x,
                                                 const float* __restrict__ g,
                                                 const float* __restrict__ b,
                                                 void* __restrict__ out) {
    int row = blockIdx.x * 4 + (threadIdx.x >> 6);
    int lane = threadIdx.x & 63;
    const float4* xr = (const float4*)(x + (size_t)row * DMODEL);
    float4 v0 = xr[lane], v1 = xr[lane + 64];
    float s = v0.x + v0.y + v0.z + v0.w + v1.x + v1.y + v1.z + v1.w;
    float sq = v0.x * v0.x + v0.y * v0.y + v0.z * v0.z + v0.w * v0.w +
               v1.x * v1.x + v1.y * v1.y + v1.z * v1.z + v1.w * v1.w;
#pragma unroll
    for (int m = 1; m < 64; m <<= 1) {
        s += __shfl_xor(s, m);
        sq += __shfl_xor(sq, m);
    }
    float mean = s * (1.0f / DMODEL);
    float var = sq * (1.0f / DMODEL) - mean * mean;
    float rstd = rsqrtf(var + 1e-5f);
    const float4* g4 = (const float4*)g;
    const float4* b4 = (const float4*)b;
    float4 ga = g4[lane], gb = g4[lane + 64], ba = b4[lane], bb = b4[lane + 64];
    float4 r0, r1;
    r0.x = (v0.x - mean) * rstd * ga.x + ba.x;
    r0.y = (v0.y - mean) * rstd * ga.y + ba.y;
    r0.z = (v0.z - mean) * rstd * ga.z + ba.z;
    r0.w = (v0.w - mean) * rstd * ga.w + ba.w;
    r1.x = (v1.x - mean) * rstd * gb.x + bb.x;
    r1.y = (v1.y - mean) * rstd * gb.y + bb.y;
    r1.z = (v1.z - mean) * rstd * gb.z + bb.z;
    r1.w = (v1.w - mean) * rstd * gb.w + bb.w;
    if (OUT_BF16) {
        ushort4 o0, o1;
        o0.x = f2bf(r0.x); o0.y = f2bf(r0.y); o0.z = f2bf(r0.z); o0.w = f2bf(r0.w);
        o1.x = f2bf(r1.x); o1.y = f2bf(r1.y); o1.z = f2bf(r1.z); o1.w = f2bf(r1.w);
        ((ushort4*)out)[(size_t)row * 128 + lane] = o0;
        ((ushort4*)out)[(size_t)row * 128 + 64 + lane] = o1;
    } else {
        ((float4*)out)[(size_t)row * 128 + lane] = r0;
        ((float4*)out)[(size_t)row * 128 + 64 + lane] = r1;
    }
}

// ------- shared GEMM core: (MT*32)x(NT*32) tile, BK=64, XOR-swizzled LDS -------
// v2: double-buffered LDS, ONE barrier per K-chunk, counted-wait pipeline (T3-min).
// Per chunk: {vmcnt(0) waits chunk i (issued one compute phase ago) -> s_barrier ->
// issue DMA chunk i+1 into other buffer -> compute chunk i}. DMA latency hides under
// the previous chunk's 64 MFMAs instead of draining at a barrier.
template <int MT, int NT>
__device__ __forceinline__ void gemm_core(const u16* __restrict__ A, const u16* __restrict__ Bt,
                                          int K, v4f (&acc)[MT][NT]) {
    constexpr int BM = MT * 32;
    constexpr int BN = NT * 32;
    __shared__ u16 As[2][BM * 64];
    __shared__ u16 Bs[2][BN * 64];
    int tid = threadIdx.x;
    int n0 = blockIdx.x * BN, m0 = blockIdx.y * BM;
    int w = tid >> 6, lane = tid & 63;
    int wr = (w >> 1) * (BM / 2), wc = (w & 1) * (BN / 2);
    int lr = lane & 15, lq = lane >> 4;
    int r8 = lane >> 3, cb = lane & 7;
    int scol = (cb ^ r8) * 8;

    v4f zero = {0.f, 0.f, 0.f, 0.f};
#pragma unroll
    for (int i = 0; i < MT; i++)
#pragma unroll
        for (int j = 0; j < NT; j++) acc[i][j] = zero;

    const u16* gA = A + (size_t)(m0 + (MT * 8) * w + r8) * K + scol;
    const u16* gB = Bt + (size_t)(n0 + (NT * 8) * w + r8) * K + scol;
    int nch = K >> 6;

    // prologue: chunk 0 -> buffer 0
#pragma unroll
    for (int j = 0; j < MT; j++) gl16(gA + (size_t)j * 8 * K, &As[0][((MT * 8) * w + j * 8) * 64]);
#pragma unroll
    for (int j = 0; j < NT; j++) gl16(gB + (size_t)j * 8 * K, &Bs[0][((NT * 8) * w + j * 8) * 64]);
    gA += 64; gB += 64;

    for (int ci = 0; ci < nch; ci++) {
        // only chunk ci's loads are outstanding here (ci+1 not yet issued) -> this
        // waits exactly for the DMA issued one full compute phase ago.
        asm volatile("s_waitcnt vmcnt(0)" ::: "memory");
        __builtin_amdgcn_s_barrier();        // all waves: buf[ci&1] ready; compute ci-1 done
        __builtin_amdgcn_sched_barrier(0);   // pin issue + reads below the barrier
        if (ci + 1 < nch) {                  // issue ci+1 into the buffer compute ci-1 used
            u16* dA = &As[(ci + 1) & 1][0];
            u16* dB = &Bs[(ci + 1) & 1][0];
#pragma unroll
            for (int j = 0; j < MT; j++) gl16(gA + (size_t)j * 8 * K, dA + ((MT * 8) * w + j * 8) * 64);
#pragma unroll
            for (int j = 0; j < NT; j++) gl16(gB + (size_t)j * 8 * K, dB + ((NT * 8) * w + j * 8) * 64);
            gA += 64; gB += 64;
        }
        const u16* cA = &As[ci & 1][0];
        const u16* cB = &Bs[ci & 1][0];
#pragma unroll
        for (int kk = 0; kk < 2; kk++) {
            int xb = ((kk * 4 + lq) ^ (lr & 7)) * 8;
            v8bf af[MT], bfr[NT];
#pragma unroll
            for (int i = 0; i < MT; i++)
                af[i] = *(const v8bf*)&cA[(wr + i * 16 + lr) * 64 + xb];
#pragma unroll
            for (int j = 0; j < NT; j++)
                bfr[j] = *(const v8bf*)&cB[(wc + j * 16 + lr) * 64 + xb];
#pragma unroll
            for (int mt = 0; mt < MT; mt++)
#pragma unroll
                for (int nt = 0; nt < NT; nt++)
                    acc[mt][nt] = __builtin_amdgcn_mfma_f32_16x16x32_bf16(af[mt], bfr[nt], acc[mt][nt], 0, 0, 0);
        }
    }
}

// ---- input projection: fp32 out + bias + sinusoid PE (N=512, 128x64) ----
__global__ __launch_bounds__(256) void gemm_in_kernel(const u16* __restrict__ A,
                                                      const u16* __restrict__ Bt,
                                                      const float* __restrict__ bias,
                                                      float* __restrict__ Out, int K) {
    v4f acc[4][2];
    gemm_core<4, 2>(A, Bt, K, acc);
    int tid = threadIdx.x, w = tid >> 6, lane = tid & 63;
    int lr = lane & 15, lq = lane >> 4;
    int wr = (w >> 1) * 64, wc = (w & 1) * 32;
    int n0 = blockIdx.x * 64, m0 = blockIdx.y * 128;
#pragma unroll
    for (int mt = 0; mt < 4; mt++) {
#pragma unroll
        for (int nt = 0; nt < 2; nt++) {
            int col = n0 + wc + nt * 16 + lr;
            float bcol = bias[col];
            float freq = __builtin_amdgcn_exp2f((float)(col & ~1) * (-0.025953277f));
#pragma unroll
            for (int reg = 0; reg < 4; reg++) {
                int row = m0 + wr + mt * 16 + lq * 4 + reg;
                float rev = (float)(row & (S_LEN - 1)) * freq * 0.15915494309189535f;
                float fr = __builtin_amdgcn_fractf(rev);
                float pe = (col & 1) ? __builtin_amdgcn_cosf(fr) : __builtin_amdgcn_sinf(fr);
                Out[(size_t)row * DMODEL + col] = acc[mt][nt][reg] + bcol + pe;
            }
        }
    }
}

// ---- fused QKV projection: N=1536 (128x128); segment block-uniform ----
__global__ __launch_bounds__(256) void gemm_qkv_kernel(const u16* __restrict__ A,
                                                       const u16* __restrict__ Bt,
                                                       const float* __restrict__ bq,
                                                       const float* __restrict__ bk,
                                                       const float* __restrict__ bv,
                                                       u16* __restrict__ Qo,
                                                       u16* __restrict__ Ko,
                                                       u16* __restrict__ Vto, int K) {
    v4f acc[4][4];
    gemm_core<4, 4>(A, Bt, K, acc);
    int tid = threadIdx.x, w = tid >> 6, lane = tid & 63;
    int lr = lane & 15, lq = lane >> 4;
    int wr = (w >> 1) * 64, wc = (w & 1) * 64;
    int n0 = blockIdx.x * 128, m0 = blockIdx.y * 128;
    int seg = n0 >> 9;
#pragma unroll
    for (int mt = 0; mt < 4; mt++) {
#pragma unroll
        for (int nt = 0; nt < 4; nt++) {
            int col = (n0 + wc + nt * 16 + lr) & (DMODEL - 1);
            if (seg == 0) {
                float bcol = bq[col];
#pragma unroll
                for (int reg = 0; reg < 4; reg++) {
                    int row = m0 + wr + mt * 16 + lq * 4 + reg;
                    Qo[(size_t)row * DMODEL + col] = f2bf((acc[mt][nt][reg] + bcol) * QSCALE);
                }
            } else if (seg == 1) {
                float bcol = bk[col];
#pragma unroll
                for (int reg = 0; reg < 4; reg++) {
                    int row = m0 + wr + mt * 16 + lq * 4 + reg;
                    Ko[(size_t)row * DMODEL + col] = f2bf(acc[mt][nt][reg] + bcol);
                }
            } else {
                float bcol = bv[col];
                int row0 = m0 + wr + mt * 16 + lq * 4;
                int bb = row0 >> 10, s0 = row0 & (S_LEN - 1);
                ushort4 o;
                o.x = f2bf(acc[mt][nt][0] + bcol);
                o.y = f2bf(acc[mt][nt][1] + bcol);
                o.z = f2bf(acc[mt][nt][2] + bcol);
                o.w = f2bf(acc[mt][nt][3] + bcol);
                *(ushort4*)(Vto + ((size_t)(bb * DMODEL + col)) * S_LEN + s0) = o;
            }
        }
    }
}

// ---- FFN1: bf16 out + bias + ReLU (N=2048, 128x128 tile) ----
__global__ __launch_bounds__(256) void gemm_relu_kernel(const u16* __restrict__ A,
                                                        const u16* __restrict__ Bt,
                                                        const float* __restrict__ bias,
                                                        u16* __restrict__ Out, int N, int K) {
    v4f acc[4][4];
    gemm_core<4, 4>(A, Bt, K, acc);
    int tid = threadIdx.x, w = tid >> 6, lane = tid & 63;
    int lr = lane & 15, lq = lane >> 4;
    int wr = (w >> 1) * 64, wc = (w & 1) * 64;
    int n0 = blockIdx.x * 128, m0 = blockIdx.y * 128;
#pragma unroll
    for (int mt = 0; mt < 4; mt++) {
#pragma unroll
        for (int nt = 0; nt < 4; nt++) {
            int col = n0 + wc + nt * 16 + lr;
            float bcol = bias[col];
#pragma unroll
            for (int reg = 0; reg < 4; reg++) {
                int row = m0 + wr + mt * 16 + lq * 4 + reg;
                Out[(size_t)row * N + col] = f2bf(fmaxf(acc[mt][nt][reg] + bcol, 0.0f));
            }
        }
    }
}

// ---- O-proj / FFN2: fp32 out + bias + residual in-place (N=512, 128x64) ----
__global__ __launch_bounds__(256) void gemm_res_kernel(const u16* __restrict__ A,
                                                       const u16* __restrict__ Bt,
                                                       const float* __restrict__ bias,
                                                       float* __restrict__ Out, int K) {
    v4f acc[4][2];
    gemm_core<4, 2>(A, Bt, K, acc);
    int tid = threadIdx.x, w = tid >> 6, lane = tid & 63;
    int lr = lane & 15, lq = lane >> 4;
    int wr = (w >> 1) * 64, wc = (w & 1) * 32;
    int n0 = blockIdx.x * 64, m0 = blockIdx.y * 128;
#pragma unroll
    for (int mt = 0; mt < 4; mt++) {
#pragma unroll
        for (int nt = 0; nt < 2; nt++) {
            int col = n0 + wc + nt * 16 + lr;
            float bcol = bias[col];
#pragma unroll
            for (int reg = 0; reg < 4; reg++) {
                int row = m0 + wr + mt * 16 + lq * 4 + reg;
                size_t idx = (size_t)row * DMODEL + col;
                Out[idx] = Out[idx] + acc[mt][nt][reg] + bcol;
            }
        }
    }
}

// -------- MFMA flash attention v11: no split-K, in-register P, counted-vmcnt pipeline --------
__global__ __launch_bounds__(256, 4) void fattn_kernel(const u16* __restrict__ Qg,
                                                       const u16* __restrict__ Kg,
                                                       const u16* __restrict__ Vtg,
                                                       const float* __restrict__ rb,
                                                       const int* __restrict__ lengths,
                                                       u16* __restrict__ O) {
    int bid = blockIdx.x;
    int wg = (bid & 7) * 64 + (bid >> 3);
    int i = wg & 63;
    int h = wg >> 6;            // XCD-local head
    int b = i & 7;              // interleaved batch -> len-balanced CUs
    int qt = (i >> 3) & 7;
    int tid = threadIdx.x, w = tid >> 6, lane = tid & 63;
    int lr = lane & 15, lq = lane >> 4;
    __shared__ u16 Ks[3][64 * 64];
    __shared__ u16 Vs[3][64 * 64];
    __shared__ float rbs[128];
    int len = lengths[b];
    if (tid < 127) rbs[tid] = rb[h * 127 + tid] * 1.4426950408889634f;  // fold log2(e)

    int nchunks = (len + 63) >> 6;   // >= 8 (len >= 512)

    int qw = qt * 128 + w * 32;   // wave's 32 q rows
    v8bf qa[2][2];                // B-operand: rows q = qw + ntq*16 + lr
#pragma unroll
    for (int ntq = 0; ntq < 2; ntq++) {
        size_t qrow = ((size_t)(b * S_LEN + qw + ntq * 16 + lr)) * DMODEL + h * DK;
        qa[ntq][0] = *(const v8bf*)(Qg + qrow + lq * 8);
        qa[ntq][1] = *(const v8bf*)(Qg + qrow + 32 + lq * 8);
    }

    v4f zero = {0.f, 0.f, 0.f, 0.f};
    v4f Oacc[4][2];   // [dtile][ntq]: O^T -> lane holds q=lr col, d=dt*16+lq*4+r rows
#pragma unroll
    for (int dt = 0; dt < 4; dt++)
#pragma unroll
        for (int nt = 0; nt < 2; nt++) Oacc[dt][nt] = zero;
    float lsum[2] = {0.f, 0.f};

    const u16* Kbase = Kg + ((size_t)b * S_LEN) * DMODEL + h * DK;
    const u16* Vbase = Vtg + ((size_t)(b * DMODEL + h * DK)) * S_LEN;
    int r8 = lane >> 3, cb = lane & 7;
    int swz = (cb ^ r8) * 8;

    // prologue: DMA chunks 0,1 into buffers 0,1 (nchunks >= 8)
#pragma unroll
    for (int j = 0; j < 2; j++) {
        int row0 = w * 16 + j * 8;
        gl16(Kbase + (size_t)(row0 + r8) * DMODEL + swz, Ks[0] + row0 * 64);
        gl16(Vbase + (size_t)(row0 + r8) * S_LEN + swz, Vs[0] + row0 * 64);
    }
#pragma unroll
    for (int j = 0; j < 2; j++) {
        int row0 = w * 16 + j * 8;
        gl16(Kbase + (size_t)(64 + row0 + r8) * DMODEL + swz, Ks[1] + row0 * 64);
        gl16(Vbase + (size_t)(row0 + r8) * S_LEN + 64 + swz, Vs[1] + row0 * 64);
    }
    __syncthreads();   // one-time full drain: c0,c1 + rbs staged and visible

    u16 *KsA = Ks[0], *VsA = Vs[0];   // current compute buffer
    u16 *KsB = Ks[1], *VsB = Vs[1];   // next (in flight or landed)
    u16 *KsC = Ks[2], *VsC = Vs[2];   // landing slot for c(i+2)

    for (int ci = 0; ci < nchunks; ci++) {
        int kb0 = ci * 64;
        if (ci > 0) {
            if (ci + 1 < nchunks) asm volatile("s_waitcnt vmcnt(4)" ::: "memory");
            else                  asm volatile("s_waitcnt vmcnt(0)" ::: "memory");
            __builtin_amdgcn_s_barrier();        // all waves: buf A ready; compute c(ci-1) done
            __builtin_amdgcn_sched_barrier(0);   // pin issue below the barrier
        }
        if (ci + 2 < nchunks) {   // issue c(ci+2) into C (overwrites c(ci-1)'s buffer, now safe)
            int nk = kb0 + 128;
#pragma unroll
            for (int j = 0; j < 2; j++) {
                int row0 = w * 16 + j * 8;
                gl16(Kbase + (size_t)(nk + row0 + r8) * DMODEL + swz, KsC + row0 * 64);
                gl16(Vbase + (size_t)(row0 + r8) * S_LEN + nk + swz, VsC + row0 * 64);
            }
        }
        const u16* Ksc = KsA;
        const u16* Vsc = VsA;

        // S^T = K @ Q^T : lane holds key = kb0+mtk*16+lq*4+r (rows), q = qw+ntq*16+lr (cols)
        v4f S[4][2];
        __builtin_amdgcn_s_setprio(1);
#pragma unroll
        for (int mtk = 0; mtk < 4; mtk++) {
            int xb0 = (lq ^ (lr & 7)) * 8;
            int xb1 = ((4 + lq) ^ (lr & 7)) * 8;
            v8bf kf0 = *(const v8bf*)&Ksc[(mtk * 16 + lr) * 64 + xb0];
            v8bf kf1 = *(const v8bf*)&Ksc[(mtk * 16 + lr) * 64 + xb1];
#pragma unroll
            for (int ntq = 0; ntq < 2; ntq++) {
                v4f s = __builtin_amdgcn_mfma_f32_16x16x32_bf16(kf0, qa[ntq][0], zero, 0, 0, 0);
                S[mtk][ntq] = __builtin_amdgcn_mfma_f32_16x16x32_bf16(kf1, qa[ntq][1], s, 0, 0, 0);
            }
        }
        __builtin_amdgcn_s_setprio(0);

        bool edge = (kb0 + 64 > len);
        int dmin = qw - (kb0 + 63), dmax = qw + 31 - kb0;
        bool perel = !(dmax <= -63 || dmin >= 63);
        float bconst = (dmax <= -63) ? rbs[0] : rbs[126];
        uint2 pks[4][2];   // packed bf16 P, lane-local (keys lq*4+r of tile mtk, q col lr)
#pragma unroll
        for (int mtk = 0; mtk < 4; mtk++) {
#pragma unroll
            for (int ntq = 0; ntq < 2; ntq++) {
                int q = qw + ntq * 16 + lr;
                float p[4];
#pragma unroll
                for (int r = 0; r < 4; r++) {
                    int key = kb0 + mtk * 16 + lq * 4 + r;
                    float s = S[mtk][ntq][r];
                    if (perel) {
                        int d = q - key;
                        d = d < -63 ? -63 : (d > 63 ? 63 : d);
                        s += rbs[d + 63];
                    } else {
                        s += bconst;
                    }
                    float pv = __builtin_amdgcn_exp2f(s);
                    if (edge && key >= len) pv = 0.f;
                    lsum[ntq] += pv;
                    p[r] = pv;
                }
                // truncating bf16 pack: relative bias cancels in normalization
                pks[mtk][ntq].x = (__float_as_uint(p[1]) & 0xffff0000u) | (__float_as_uint(p[0]) >> 16);
                pks[mtk][ntq].y = (__float_as_uint(p[3]) & 0xffff0000u) | (__float_as_uint(p[2]) >> 16);
            }
        }

        // O^T += V^T @ P^T with permuted k-order: k=lq*8+j <-> key = kh*32 + (j<4 ? lq*4+j
        // : 16+lq*4+j-4). B-frag = lane's own pks; A-frag = two swizzled b64 reads from Vs.
        __builtin_amdgcn_s_setprio(1);
#pragma unroll
        for (int kh = 0; kh < 2; kh++) {
            uint4 tp0 = {pks[kh * 2][0].x, pks[kh * 2][0].y, pks[kh * 2 + 1][0].x, pks[kh * 2 + 1][0].y};
            uint4 tp1 = {pks[kh * 2][1].x, pks[kh * 2][1].y, pks[kh * 2 + 1][1].x, pks[kh * 2 + 1][1].y};
            v8bf pb0 = *(v8bf*)&tp0;
            v8bf pb1 = *(v8bf*)&tp1;
            int gl = kh * 4 + (lq >> 1);
            int sub = (lq & 1) * 4;
#pragma unroll
            for (int dt = 0; dt < 4; dt++) {
                int drow = (dt * 16 + lr) * 64;
                uint2 lo = *(const uint2*)&Vsc[drow + ((gl ^ (lr & 7)) * 8 + sub)];
                uint2 hi = *(const uint2*)&Vsc[drow + (((gl + 2) ^ (lr & 7)) * 8 + sub)];
                uint4 tv = {lo.x, lo.y, hi.x, hi.y};
                v8bf va = *(v8bf*)&tv;
                Oacc[dt][0] = __builtin_amdgcn_mfma_f32_16x16x32_bf16(va, pb0, Oacc[dt][0], 0, 0, 0);
                Oacc[dt][1] = __builtin_amdgcn_mfma_f32_16x16x32_bf16(va, pb1, Oacc[dt][1], 0, 0, 0);
            }
        }
        __builtin_amdgcn_s_setprio(0);

        // rotate buffers: A <- B <- C <- A
        u16* t;
        t = KsA; KsA = KsB; KsB = KsC; KsC = t;
        t = VsA; VsA = VsB; VsB = VsC; VsC = t;
    }

    // reduce row sums across key quads (lane then holds total for q = qw+ntq*16+lr)
    float inv[2];
#pragma unroll
    for (int ntq = 0; ntq < 2; ntq++) {
        float s = lsum[ntq];
        s += __shfl_xor(s, 16);
        s += __shfl_xor(s, 32);
        inv[ntq] = 1.0f / s;
    }
    // normalized O (bf16): lane writes 4 consecutive d per tile -> 8B stores
#pragma unroll
    for (int dt = 0; dt < 4; dt++) {
#pragma unroll
        for (int ntq = 0; ntq < 2; ntq++) {
            size_t off = (size_t)(b * S_LEN + qw + ntq * 16 + lr) * DMODEL + h * DK + dt * 16 + lq * 4;
            ushort4 o;
            o.x = f2bf(Oacc[dt][ntq][0] * inv[ntq]);
            o.y = f2bf(Oacc[dt][ntq][1] * inv[ntq]);
            o.z = f2bf(Oacc[dt][ntq][2] * inv[ntq]);
            o.w = f2bf(Oacc[dt][ntq][3] * inv[ntq]);
            *(ushort4*)(O + off) = o;
        }
    }
}

extern "C" void kernel_launch(void* const* d_in, const int* in_sizes, int n_in,
                              void* d_out, int out_size, void* d_ws, size_t ws_size,
                              hipStream_t stream) {
    const float* inputs   = (const float*)d_in[0];
    const int*   lengths  = (const int*)d_in[1];
    const float* W_in     = (const float*)d_in[2];
    const float* b_in     = (const float*)d_in[3];
    const float* Wq       = (const float*)d_in[4];
    const float* bq       = (const float*)d_in[5];
    const float* Wk       = (const float*)d_in[6];
    const float* bk       = (const float*)d_in[7];
    const float* Wv       = (const float*)d_in[8];
    const float* bv       = (const float*)d_in[9];
    const float* Wo       = (const float*)d_in[10];
    const float* bo       = (const float*)d_in[11];
    const float* rel_bias = (const float*)d_in[12];
    const float* W1       = (const float*)d_in[13];
    const float* b1       = (const float*)d_in[14];
    const float* W2       = (const float*)d_in[15];
    const float* b2       = (const float*)d_in[16];
    const float* g1       = (const float*)d_in[17];
    const float* be1      = (const float*)d_in[18];
    const float* g2       = (const float*)d_in[19];
    const float* be2      = (const float*)d_in[20];
    const float* gf       = (const float*)d_in[21];
    const float* bef      = (const float*)d_in[22];

    // ---- workspace layout (tight, liveness-based unions; total ≈ 71.6 MB) ----
    char* ws = (char*)d_ws;
    float* xbuf = (float*)ws;          ws += (size_t)MROWS * DMODEL * 4;   // 16.78MB residual fp32
    u16* hbuf   = (u16*)ws;            ws += (size_t)MROWS * DMODEL * 2;   // 8.39MB LN-out / attn-out
    u16* aobuf  = hbuf;                                                    // alias (time-shared)
    u16* qbf    = (u16*)ws;            ws += (size_t)MROWS * FF_DIM * 2;   // 32MB union region
    u16* kbf    = qbf + (size_t)MROWS * DMODEL;
    u16* vtbf   = kbf + (size_t)MROWS * DMODEL;
    u16* tbuf   = qbf;                 // FFN mid (32MB) reuses q/k/vt region
    u16* inbf   = qbf;                 // bf16 inputs (4.2MB), dead before qkv writes
    u16* wt_in  = (u16*)ws;            ws += (size_t)DMODEL * IN_DIM * 2;
    u16 *qkvw[2], *wto[2], *wt1[2], *wt2[2];
    for (int l = 0; l < 2; l++) { qkvw[l] = (u16*)ws; ws += (size_t)3 * DMODEL * DMODEL * 2; }
    for (int l = 0; l < 2; l++) { wto[l] = (u16*)ws; ws += (size_t)DMODEL * DMODEL * 2; }
    for (int l = 0; l < 2; l++) { wt1[l] = (u16*)ws; ws += (size_t)FF_DIM * DMODEL * 2; }
    for (int l = 0; l < 2; l++) { wt2[l] = (u16*)ws; ws += (size_t)DMODEL * FF_DIM * 2; }

    TArgs ta;
    int ti = 0, acct = 0;
    auto add = [&](const float* s, u16* d, int K, int N) {
        ta.d[ti] = {s, d, K, N};
        ta.start[ti] = acct;
        int tn = N / 32;
        int l2 = 31 - __builtin_clz((unsigned)tn);
        ta.l2tn[ti] = l2;
        acct += (K / 32) * tn;
        ti++;
    };
    add(W_in, wt_in, IN_DIM, DMODEL);
    for (int l = 0; l < 2; l++) {
        add(Wq + (size_t)l * DMODEL * DMODEL, qkvw[l], DMODEL, DMODEL);
        add(Wk + (size_t)l * DMODEL * DMODEL, qkvw[l] + (size_t)DMODEL * DMODEL, DMODEL, DMODEL);
        add(Wv + (size_t)l * DMODEL * DMODEL, qkvw[l] + (size_t)2 * DMODEL * DMODEL, DMODEL, DMODEL);
        add(Wo + (size_t)l * DMODEL * DMODEL, wto[l], DMODEL, DMODEL);
        add(W1 + (size_t)l * DMODEL * FF_DIM, wt1[l], DMODEL, FF_DIM);
        add(W2 + (size_t)l * FF_DIM * DMODEL, wt2[l], FF_DIM, DMODEL);
    }
    ta.start[13] = acct;

    conv_bf16_kernel<<<dim3((MROWS * IN_DIM / 4 + 255) / 256), 256, 0, stream>>>(
        inputs, inbf, MROWS * IN_DIM / 4);
    transpose_conv_kernel<<<dim3(acct), dim3(32, 8), 0, stream>>>(ta);

    gemm_in_kernel<<<dim3(DMODEL / 64, MROWS / 128), 256, 0, stream>>>(
        inbf, wt_in, b_in, xbuf, IN_DIM);

    for (int l = 0; l < 2; l++) {
        ln_kernel<true><<<MROWS / 4, 256, 0, stream>>>(xbuf, g1 + l * DMODEL, be1 + l * DMODEL, hbuf);
        gemm_qkv_kernel<<<dim3(3 * DMODEL / 128, MROWS / 128), 256, 0, stream>>>(
            hbuf, qkvw[l], bq + l * DMODEL, bk + l * DMODEL, bv + l * DMODEL,
            qbf, kbf, vtbf, DMODEL);
        fattn_kernel<<<dim3(512), 256, 0, stream>>>(
            qbf, kbf, vtbf, rel_bias + (size_t)l * NHEAD * 127, lengths, aobuf);
        gemm_res_kernel<<<dim3(DMODEL / 64, MROWS / 128), 256, 0, stream>>>(
            aobuf, wto[l], bo + l * DMODEL, xbuf, DMODEL);
        ln_kernel<true><<<MROWS / 4, 256, 0, stream>>>(xbuf, g2 + l * DMODEL, be2 + l * DMODEL, hbuf);
        gemm_relu_kernel<<<dim3(FF_DIM / 128, MROWS / 128), 256, 0, stream>>>(
            hbuf, wt1[l], b1 + l * FF_DIM, tbuf, FF_DIM, DMODEL);
        gemm_res_kernel<<<dim3(DMODEL / 64, MROWS / 128), 256, 0, stream>>>(
            tbuf, wt2[l], b2 + l * DMODEL, xbuf, FF_DIM);
    }
    ln_kernel<false><<<MROWS / 4, 256, 0, stream>>>(xbuf, gf, bef, d_out);
}

// Round 9
// 438.845 us; speedup vs baseline: 1.0397x; 1.0397x over previous
//
#include <hip/hip_runtime.h>
#include <hip/hip_bf16.h>

typedef unsigned short u16;
typedef unsigned int u32;
typedef __bf16 v8bf __attribute__((ext_vector_type(8)));
typedef float v4f __attribute__((ext_vector_type(4)));

#define B_SZ 8
#define S_LEN 1024
#define IN_DIM 256
#define DMODEL 512
#define NHEAD 8
#define DK 64
#define FF_DIM 2048
#define MROWS (B_SZ * S_LEN)   // 8192
#define QSCALE 0.1803368801111204f   // 0.125 * log2(e)

__device__ __forceinline__ u16 f2bf(float f) {
    unsigned int x = __float_as_uint(f);
    unsigned int r = (x + 0x7fffu + ((x >> 16) & 1u)) >> 16;
    return (u16)r;
}
__device__ __forceinline__ float bf2f(u16 v) {
    return __uint_as_float((u32)v << 16);
}

// async global->LDS DMA, 16B per lane; lds dest is wave-uniform base + lane*16
__device__ __forceinline__ void gl16(const u16* g, u16* l) {
    __builtin_amdgcn_global_load_lds((const __attribute__((address_space(1))) unsigned int*)g,
                                     (__attribute__((address_space(3))) unsigned int*)l, 16, 0, 0);
}

// ---------------- elementwise f32 -> bf16 (inputs matrix) ----------------
__global__ __launch_bounds__(256) void conv_bf16_kernel(const float* __restrict__ in,
                                                        u16* __restrict__ out, int n4) {
    int i = blockIdx.x * 256 + threadIdx.x;
    if (i < n4) {
        float4 v = ((const float4*)in)[i];
        ushort4 o;
        o.x = f2bf(v.x); o.y = f2bf(v.y); o.z = f2bf(v.z); o.w = f2bf(v.w);
        ((ushort4*)out)[i] = o;
    }
}

// ------------- batched transpose+convert: (K,N) f32 -> (N,K) bf16 -------------
// exact tiling: flattened 1-D grid, host-computed per-desc tile offsets (no no-op blocks).
struct TDesc { const float* src; u16* dst; int K; int N; };
struct TArgs { TDesc d[13]; int start[14]; int l2tn[13]; };

__global__ void transpose_conv_kernel(TArgs args) {
    int bid = blockIdx.x;
    int z = 0;
    while (z < 12 && bid >= args.start[z + 1]) z++;
    TDesc t = args.d[z];
    int local = bid - args.start[z];
    int l2 = args.l2tn[z];
    int k0 = (local >> l2) << 5;
    int n0 = (local & ((1 << l2) - 1)) << 5;
    __shared__ float tile[32][33];
    int tx = threadIdx.x, ty = threadIdx.y;
#pragma unroll
    for (int j = 0; j < 4; j++) {
        int k = k0 + ty + j * 8;
        tile[ty + j * 8][tx] = t.src[(size_t)k * t.N + n0 + tx];
    }
    __syncthreads();
#pragma unroll
    for (int j = 0; j < 4; j++) {
        int n = n0 + ty + j * 8;
        t.dst[(size_t)n * t.K + k0 + tx] = f2bf(tile[tx][ty + j * 8]);
    }
}

// ------- LayerNorm: bf16 residual in -> bf16 (or fp32) out -------
// input row = 512 bf16 = 1024B -> exactly one uint4 (8 elems) per lane.
template <bool OUT_BF16>
__global__ __launch_bounds__(256) void ln_kernel(const u16* __restrict__ x,
                                                 const float* __restrict__ g,
                                                 const float* __restrict__ b,
                                                 void* __restrict__ out) {
    int row = blockIdx.x * 4 + (threadIdx.x >> 6);
    int lane = threadIdx.x & 63;
    uint4 v = ((const uint4*)(x + (size_t)row * DMODEL))[lane];
    float f[8];
    f[0] = __uint_as_float(v.x << 16); f[1] = __uint_as_float(v.x & 0xffff0000u);
    f[2] = __uint_as_float(v.y << 16); f[3] = __uint_as_float(v.y & 0xffff0000u);
    f[4] = __uint_as_float(v.z << 16); f[5] = __uint_as_float(v.z & 0xffff0000u);
    f[6] = __uint_as_float(v.w << 16); f[7] = __uint_as_float(v.w & 0xffff0000u);
    float s = 0.f, sq = 0.f;
#pragma unroll
    for (int i = 0; i < 8; i++) { s += f[i]; sq += f[i] * f[i]; }
#pragma unroll
    for (int m = 1; m < 64; m <<= 1) {
        s += __shfl_xor(s, m);
        sq += __shfl_xor(sq, m);
    }
    float mean = s * (1.0f / DMODEL);
    float var = sq * (1.0f / DMODEL) - mean * mean;
    float rstd = rsqrtf(var + 1e-5f);
    const float4* g4 = (const float4*)g;
    const float4* b4 = (const float4*)b;
    float4 ga = g4[lane * 2], gb = g4[lane * 2 + 1];
    float4 ba = b4[lane * 2], bb = b4[lane * 2 + 1];
    float r[8];
    r[0] = (f[0] - mean) * rstd * ga.x + ba.x;
    r[1] = (f[1] - mean) * rstd * ga.y + ba.y;
    r[2] = (f[2] - mean) * rstd * ga.z + ba.z;
    r[3] = (f[3] - mean) * rstd * ga.w + ba.w;
    r[4] = (f[4] - mean) * rstd * gb.x + bb.x;
    r[5] = (f[5] - mean) * rstd * gb.y + bb.y;
    r[6] = (f[6] - mean) * rstd * gb.z + bb.z;
    r[7] = (f[7] - mean) * rstd * gb.w + bb.w;
    if (OUT_BF16) {
        uint4 o;
        o.x = (u32)f2bf(r[0]) | ((u32)f2bf(r[1]) << 16);
        o.y = (u32)f2bf(r[2]) | ((u32)f2bf(r[3]) << 16);
        o.z = (u32)f2bf(r[4]) | ((u32)f2bf(r[5]) << 16);
        o.w = (u32)f2bf(r[6]) | ((u32)f2bf(r[7]) << 16);
        ((uint4*)out)[(size_t)row * 64 + lane] = o;
    } else {
        float4 o0 = {r[0], r[1], r[2], r[3]};
        float4 o1 = {r[4], r[5], r[6], r[7]};
        ((float4*)out)[(size_t)row * 128 + lane * 2] = o0;
        ((float4*)out)[(size_t)row * 128 + lane * 2 + 1] = o1;
    }
}

// ------- shared GEMM core: (MT*32) x (NT*32) tile, BK=64, XOR-swizzled LDS -------
// (r7 known-best structure: single-buffered, 2 barriers/chunk; inter-block overlap
// hides the drain at 3-5 blocks/CU — explicit dbuf measured neutral-to-negative, r8)
template <int MT, int NT>
__device__ __forceinline__ void gemm_core(const u16* __restrict__ A, const u16* __restrict__ Bt,
                                          int K, v4f (&acc)[MT][NT]) {
    constexpr int BM = MT * 32;
    constexpr int BN = NT * 32;
    __shared__ u16 As[BM * 64];
    __shared__ u16 Bs[BN * 64];
    int tid = threadIdx.x;
    int n0 = blockIdx.x * BN, m0 = blockIdx.y * BM;
    int w = tid >> 6, lane = tid & 63;
    int wr = (w >> 1) * (BM / 2), wc = (w & 1) * (BN / 2);
    int lr = lane & 15, lq = lane >> 4;
    int r8 = lane >> 3, cb = lane & 7;
    int scol = (cb ^ r8) * 8;

    v4f zero = {0.f, 0.f, 0.f, 0.f};
#pragma unroll
    for (int i = 0; i < MT; i++)
#pragma unroll
        for (int j = 0; j < NT; j++) acc[i][j] = zero;

    const u16* gA[MT]; u16* lA[MT];
#pragma unroll
    for (int j = 0; j < MT; j++) {
        int row0 = (MT * 8) * w + j * 8;
        gA[j] = A + (size_t)(m0 + row0 + r8) * K + scol;
        lA[j] = As + row0 * 64;
    }
    const u16* gB[NT]; u16* lB[NT];
#pragma unroll
    for (int j = 0; j < NT; j++) {
        int row0 = (NT * 8) * w + j * 8;
        gB[j] = Bt + (size_t)(n0 + row0 + r8) * K + scol;
        lB[j] = Bs + row0 * 64;
    }

    for (int k0 = 0; k0 < K; k0 += 64) {
#pragma unroll
        for (int j = 0; j < MT; j++) gl16(gA[j], lA[j]);
#pragma unroll
        for (int j = 0; j < NT; j++) gl16(gB[j], lB[j]);
        __syncthreads();   // vmcnt drain -> tiles ready
#pragma unroll
        for (int kk = 0; kk < 2; kk++) {
            int xb = ((kk * 4 + lq) ^ (lr & 7)) * 8;
            v8bf af[MT], bfr[NT];
#pragma unroll
            for (int i = 0; i < MT; i++)
                af[i] = *(const v8bf*)&As[(wr + i * 16 + lr) * 64 + xb];
#pragma unroll
            for (int j = 0; j < NT; j++)
                bfr[j] = *(const v8bf*)&Bs[(wc + j * 16 + lr) * 64 + xb];
#pragma unroll
            for (int mt = 0; mt < MT; mt++)
#pragma unroll
                for (int nt = 0; nt < NT; nt++)
                    acc[mt][nt] = __builtin_amdgcn_mfma_f32_16x16x32_bf16(af[mt], bfr[nt], acc[mt][nt], 0, 0, 0);
        }
        __syncthreads();   // frag reads done before next DMA overwrites
#pragma unroll
        for (int j = 0; j < MT; j++) gA[j] += 64;
#pragma unroll
        for (int j = 0; j < NT; j++) gB[j] += 64;
    }
}

// ---- input projection: bf16 residual out + bias + sinusoid PE (N=512, 128x64) ----
__global__ __launch_bounds__(256) void gemm_in_kernel(const u16* __restrict__ A,
                                                      const u16* __restrict__ Bt,
                                                      const float* __restrict__ bias,
                                                      u16* __restrict__ Out, int K) {
    v4f acc[4][2];
    gemm_core<4, 2>(A, Bt, K, acc);
    int tid = threadIdx.x, w = tid >> 6, lane = tid & 63;
    int lr = lane & 15, lq = lane >> 4;
    int wr = (w >> 1) * 64, wc = (w & 1) * 32;
    int n0 = blockIdx.x * 64, m0 = blockIdx.y * 128;
#pragma unroll
    for (int mt = 0; mt < 4; mt++) {
#pragma unroll
        for (int nt = 0; nt < 2; nt++) {
            int col = n0 + wc + nt * 16 + lr;
            float bcol = bias[col];
            float freq = __builtin_amdgcn_exp2f((float)(col & ~1) * (-0.025953277f));
#pragma unroll
            for (int reg = 0; reg < 4; reg++) {
                int row = m0 + wr + mt * 16 + lq * 4 + reg;
                float rev = (float)(row & (S_LEN - 1)) * freq * 0.15915494309189535f;
                float fr = __builtin_amdgcn_fractf(rev);
                float pe = (col & 1) ? __builtin_amdgcn_cosf(fr) : __builtin_amdgcn_sinf(fr);
                Out[(size_t)row * DMODEL + col] = f2bf(acc[mt][nt][reg] + bcol + pe);
            }
        }
    }
}

// ---- fused QKV projection: N=1536 (128x128); segment block-uniform ----
__global__ __launch_bounds__(256) void gemm_qkv_kernel(const u16* __restrict__ A,
                                                       const u16* __restrict__ Bt,
                                                       const float* __restrict__ bq,
                                                       const float* __restrict__ bk,
                                                       const float* __restrict__ bv,
                                                       u16* __restrict__ Qo,
                                                       u16* __restrict__ Ko,
                                                       u16* __restrict__ Vto, int K) {
    v4f acc[4][4];
    gemm_core<4, 4>(A, Bt, K, acc);
    int tid = threadIdx.x, w = tid >> 6, lane = tid & 63;
    int lr = lane & 15, lq = lane >> 4;
    int wr = (w >> 1) * 64, wc = (w & 1) * 64;
    int n0 = blockIdx.x * 128, m0 = blockIdx.y * 128;
    int seg = n0 >> 9;
#pragma unroll
    for (int mt = 0; mt < 4; mt++) {
#pragma unroll
        for (int nt = 0; nt < 4; nt++) {
            int col = (n0 + wc + nt * 16 + lr) & (DMODEL - 1);
            if (seg == 0) {
                float bcol = bq[col];
#pragma unroll
                for (int reg = 0; reg < 4; reg++) {
                    int row = m0 + wr + mt * 16 + lq * 4 + reg;
                    Qo[(size_t)row * DMODEL + col] = f2bf((acc[mt][nt][reg] + bcol) * QSCALE);
                }
            } else if (seg == 1) {
                float bcol = bk[col];
#pragma unroll
                for (int reg = 0; reg < 4; reg++) {
                    int row = m0 + wr + mt * 16 + lq * 4 + reg;
                    Ko[(size_t)row * DMODEL + col] = f2bf(acc[mt][nt][reg] + bcol);
                }
            } else {
                float bcol = bv[col];
                int row0 = m0 + wr + mt * 16 + lq * 4;
                int bb = row0 >> 10, s0 = row0 & (S_LEN - 1);
                ushort4 o;
                o.x = f2bf(acc[mt][nt][0] + bcol);
                o.y = f2bf(acc[mt][nt][1] + bcol);
                o.z = f2bf(acc[mt][nt][2] + bcol);
                o.w = f2bf(acc[mt][nt][3] + bcol);
                *(ushort4*)(Vto + ((size_t)(bb * DMODEL + col)) * S_LEN + s0) = o;
            }
        }
    }
}

// ---- FFN1: bf16 out + bias + ReLU (N=2048, 128x128 tile) ----
__global__ __launch_bounds__(256) void gemm_relu_kernel(const u16* __restrict__ A,
                                                        const u16* __restrict__ Bt,
                                                        const float* __restrict__ bias,
                                                        u16* __restrict__ Out, int N, int K) {
    v4f acc[4][4];
    gemm_core<4, 4>(A, Bt, K, acc);
    int tid = threadIdx.x, w = tid >> 6, lane = tid & 63;
    int lr = lane & 15, lq = lane >> 4;
    int wr = (w >> 1) * 64, wc = (w & 1) * 64;
    int n0 = blockIdx.x * 128, m0 = blockIdx.y * 128;
#pragma unroll
    for (int mt = 0; mt < 4; mt++) {
#pragma unroll
        for (int nt = 0; nt < 4; nt++) {
            int col = n0 + wc + nt * 16 + lr;
            float bcol = bias[col];
#pragma unroll
            for (int reg = 0; reg < 4; reg++) {
                int row = m0 + wr + mt * 16 + lq * 4 + reg;
                Out[(size_t)row * N + col] = f2bf(fmaxf(acc[mt][nt][reg] + bcol, 0.0f));
            }
        }
    }
}

// ---- O-proj / FFN2: bf16 residual RMW + bias (N=512, 128x64) ----
__global__ __launch_bounds__(256) void gemm_res_kernel(const u16* __restrict__ A,
                                                       const u16* __restrict__ Bt,
                                                       const float* __restrict__ bias,
                                                       u16* __restrict__ Out, int K) {
    v4f acc[4][2];
    gemm_core<4, 2>(A, Bt, K, acc);
    int tid = threadIdx.x, w = tid >> 6, lane = tid & 63;
    int lr = lane & 15, lq = lane >> 4;
    int wr = (w >> 1) * 64, wc = (w & 1) * 32;
    int n0 = blockIdx.x * 64, m0 = blockIdx.y * 128;
#pragma unroll
    for (int mt = 0; mt < 4; mt++) {
#pragma unroll
        for (int nt = 0; nt < 2; nt++) {
            int col = n0 + wc + nt * 16 + lr;
            float bcol = bias[col];
#pragma unroll
            for (int reg = 0; reg < 4; reg++) {
                int row = m0 + wr + mt * 16 + lq * 4 + reg;
                size_t idx = (size_t)row * DMODEL + col;
                Out[idx] = f2bf(bf2f(Out[idx]) + acc[mt][nt][reg] + bcol);
            }
        }
    }
}

// -------- MFMA flash attention v11: no split-K, in-register P, counted-vmcnt pipeline --------
__global__ __launch_bounds__(256, 4) void fattn_kernel(const u16* __restrict__ Qg,
                                                       const u16* __restrict__ Kg,
                                                       const u16* __restrict__ Vtg,
                                                       const float* __restrict__ rb,
                                                       const int* __restrict__ lengths,
                                                       u16* __restrict__ O) {
    int bid = blockIdx.x;
    int wg = (bid & 7) * 64 + (bid >> 3);
    int i = wg & 63;
    int h = wg >> 6;            // XCD-local head
    int b = i & 7;              // interleaved batch -> len-balanced CUs
    int qt = (i >> 3) & 7;
    int tid = threadIdx.x, w = tid >> 6, lane = tid & 63;
    int lr = lane & 15, lq = lane >> 4;
    __shared__ u16 Ks[3][64 * 64];
    __shared__ u16 Vs[3][64 * 64];
    __shared__ float rbs[128];
    int len = lengths[b];
    if (tid < 127) rbs[tid] = rb[h * 127 + tid] * 1.4426950408889634f;  // fold log2(e)

    int nchunks = (len + 63) >> 6;   // >= 8 (len >= 512)

    int qw = qt * 128 + w * 32;   // wave's 32 q rows
    v8bf qa[2][2];                // B-operand: rows q = qw + ntq*16 + lr
#pragma unroll
    for (int ntq = 0; ntq < 2; ntq++) {
        size_t qrow = ((size_t)(b * S_LEN + qw + ntq * 16 + lr)) * DMODEL + h * DK;
        qa[ntq][0] = *(const v8bf*)(Qg + qrow + lq * 8);
        qa[ntq][1] = *(const v8bf*)(Qg + qrow + 32 + lq * 8);
    }

    v4f zero = {0.f, 0.f, 0.f, 0.f};
    v4f Oacc[4][2];   // [dtile][ntq]: O^T -> lane holds q=lr col, d=dt*16+lq*4+r rows
#pragma unroll
    for (int dt = 0; dt < 4; dt++)
#pragma unroll
        for (int nt = 0; nt < 2; nt++) Oacc[dt][nt] = zero;
    float lsum[2] = {0.f, 0.f};

    const u16* Kbase = Kg + ((size_t)b * S_LEN) * DMODEL + h * DK;
    const u16* Vbase = Vtg + ((size_t)(b * DMODEL + h * DK)) * S_LEN;
    int r8 = lane >> 3, cb = lane & 7;
    int swz = (cb ^ r8) * 8;

    // prologue: DMA chunks 0,1 into buffers 0,1 (nchunks >= 8)
#pragma unroll
    for (int j = 0; j < 2; j++) {
        int row0 = w * 16 + j * 8;
        gl16(Kbase + (size_t)(row0 + r8) * DMODEL + swz, Ks[0] + row0 * 64);
        gl16(Vbase + (size_t)(row0 + r8) * S_LEN + swz, Vs[0] + row0 * 64);
    }
#pragma unroll
    for (int j = 0; j < 2; j++) {
        int row0 = w * 16 + j * 8;
        gl16(Kbase + (size_t)(64 + row0 + r8) * DMODEL + swz, Ks[1] + row0 * 64);
        gl16(Vbase + (size_t)(row0 + r8) * S_LEN + 64 + swz, Vs[1] + row0 * 64);
    }
    __syncthreads();   // one-time full drain: c0,c1 + rbs staged and visible

    u16 *KsA = Ks[0], *VsA = Vs[0];   // current compute buffer
    u16 *KsB = Ks[1], *VsB = Vs[1];   // next (in flight or landed)
    u16 *KsC = Ks[2], *VsC = Vs[2];   // landing slot for c(i+2)

    for (int ci = 0; ci < nchunks; ci++) {
        int kb0 = ci * 64;
        if (ci > 0) {
            if (ci + 1 < nchunks) asm volatile("s_waitcnt vmcnt(4)" ::: "memory");
            else                  asm volatile("s_waitcnt vmcnt(0)" ::: "memory");
            __builtin_amdgcn_s_barrier();        // all waves: buf A ready; compute c(ci-1) done
            __builtin_amdgcn_sched_barrier(0);   // pin issue below the barrier
        }
        if (ci + 2 < nchunks) {   // issue c(ci+2) into C (overwrites c(ci-1)'s buffer, now safe)
            int nk = kb0 + 128;
#pragma unroll
            for (int j = 0; j < 2; j++) {
                int row0 = w * 16 + j * 8;
                gl16(Kbase + (size_t)(nk + row0 + r8) * DMODEL + swz, KsC + row0 * 64);
                gl16(Vbase + (size_t)(row0 + r8) * S_LEN + nk + swz, VsC + row0 * 64);
            }
        }
        const u16* Ksc = KsA;
        const u16* Vsc = VsA;

        // S^T = K @ Q^T : lane holds key = kb0+mtk*16+lq*4+r (rows), q = qw+ntq*16+lr (cols)
        v4f S[4][2];
        __builtin_amdgcn_s_setprio(1);
#pragma unroll
        for (int mtk = 0; mtk < 4; mtk++) {
            int xb0 = (lq ^ (lr & 7)) * 8;
            int xb1 = ((4 + lq) ^ (lr & 7)) * 8;
            v8bf kf0 = *(const v8bf*)&Ksc[(mtk * 16 + lr) * 64 + xb0];
            v8bf kf1 = *(const v8bf*)&Ksc[(mtk * 16 + lr) * 64 + xb1];
#pragma unroll
            for (int ntq = 0; ntq < 2; ntq++) {
                v4f s = __builtin_amdgcn_mfma_f32_16x16x32_bf16(kf0, qa[ntq][0], zero, 0, 0, 0);
                S[mtk][ntq] = __builtin_amdgcn_mfma_f32_16x16x32_bf16(kf1, qa[ntq][1], s, 0, 0, 0);
            }
        }
        __builtin_amdgcn_s_setprio(0);

        bool edge = (kb0 + 64 > len);
        int dmin = qw - (kb0 + 63), dmax = qw + 31 - kb0;
        bool perel = !(dmax <= -63 || dmin >= 63);
        float bconst = (dmax <= -63) ? rbs[0] : rbs[126];
        uint2 pks[4][2];   // packed bf16 P, lane-local (keys lq*4+r of tile mtk, q col lr)
#pragma unroll
        for (int mtk = 0; mtk < 4; mtk++) {
#pragma unroll
            for (int ntq = 0; ntq < 2; ntq++) {
                int q = qw + ntq * 16 + lr;
                float p[4];
#pragma unroll
                for (int r = 0; r < 4; r++) {
                    int key = kb0 + mtk * 16 + lq * 4 + r;
                    float s = S[mtk][ntq][r];
                    if (perel) {
                        int d = q - key;
                        d = d < -63 ? -63 : (d > 63 ? 63 : d);
                        s += rbs[d + 63];
                    } else {
                        s += bconst;
                    }
                    float pv = __builtin_amdgcn_exp2f(s);
                    if (edge && key >= len) pv = 0.f;
                    lsum[ntq] += pv;
                    p[r] = pv;
                }
                // truncating bf16 pack: relative bias cancels in normalization
                pks[mtk][ntq].x = (__float_as_uint(p[1]) & 0xffff0000u) | (__float_as_uint(p[0]) >> 16);
                pks[mtk][ntq].y = (__float_as_uint(p[3]) & 0xffff0000u) | (__float_as_uint(p[2]) >> 16);
            }
        }

        // O^T += V^T @ P^T with permuted k-order: k=lq*8+j <-> key = kh*32 + (j<4 ? lq*4+j
        // : 16+lq*4+j-4). B-frag = lane's own pks; A-frag = two swizzled b64 reads from Vs.
        __builtin_amdgcn_s_setprio(1);
#pragma unroll
        for (int kh = 0; kh < 2; kh++) {
            uint4 tp0 = {pks[kh * 2][0].x, pks[kh * 2][0].y, pks[kh * 2 + 1][0].x, pks[kh * 2 + 1][0].y};
            uint4 tp1 = {pks[kh * 2][1].x, pks[kh * 2][1].y, pks[kh * 2 + 1][1].x, pks[kh * 2 + 1][1].y};
            v8bf pb0 = *(v8bf*)&tp0;
            v8bf pb1 = *(v8bf*)&tp1;
            int gl = kh * 4 + (lq >> 1);
            int sub = (lq & 1) * 4;
#pragma unroll
            for (int dt = 0; dt < 4; dt++) {
                int drow = (dt * 16 + lr) * 64;
                uint2 lo = *(const uint2*)&Vsc[drow + ((gl ^ (lr & 7)) * 8 + sub)];
                uint2 hi = *(const uint2*)&Vsc[drow + (((gl + 2) ^ (lr & 7)) * 8 + sub)];
                uint4 tv = {lo.x, lo.y, hi.x, hi.y};
                v8bf va = *(v8bf*)&tv;
                Oacc[dt][0] = __builtin_amdgcn_mfma_f32_16x16x32_bf16(va, pb0, Oacc[dt][0], 0, 0, 0);
                Oacc[dt][1] = __builtin_amdgcn_mfma_f32_16x16x32_bf16(va, pb1, Oacc[dt][1], 0, 0, 0);
            }
        }
        __builtin_amdgcn_s_setprio(0);

        // rotate buffers: A <- B <- C <- A
        u16* t;
        t = KsA; KsA = KsB; KsB = KsC; KsC = t;
        t = VsA; VsA = VsB; VsB = VsC; VsC = t;
    }

    // reduce row sums across key quads (lane then holds total for q = qw+ntq*16+lr)
    float inv[2];
#pragma unroll
    for (int ntq = 0; ntq < 2; ntq++) {
        float s = lsum[ntq];
        s += __shfl_xor(s, 16);
        s += __shfl_xor(s, 32);
        inv[ntq] = 1.0f / s;
    }
    // normalized O (bf16): lane writes 4 consecutive d per tile -> 8B stores
#pragma unroll
    for (int dt = 0; dt < 4; dt++) {
#pragma unroll
        for (int ntq = 0; ntq < 2; ntq++) {
            size_t off = (size_t)(b * S_LEN + qw + ntq * 16 + lr) * DMODEL + h * DK + dt * 16 + lq * 4;
            ushort4 o;
            o.x = f2bf(Oacc[dt][ntq][0] * inv[ntq]);
            o.y = f2bf(Oacc[dt][ntq][1] * inv[ntq]);
            o.z = f2bf(Oacc[dt][ntq][2] * inv[ntq]);
            o.w = f2bf(Oacc[dt][ntq][3] * inv[ntq]);
            *(ushort4*)(O + off) = o;
        }
    }
}

extern "C" void kernel_launch(void* const* d_in, const int* in_sizes, int n_in,
                              void* d_out, int out_size, void* d_ws, size_t ws_size,
                              hipStream_t stream) {
    const float* inputs   = (const float*)d_in[0];
    const int*   lengths  = (const int*)d_in[1];
    const float* W_in     = (const float*)d_in[2];
    const float* b_in     = (const float*)d_in[3];
    const float* Wq       = (const float*)d_in[4];
    const float* bq       = (const float*)d_in[5];
    const float* Wk       = (const float*)d_in[6];
    const float* bk       = (const float*)d_in[7];
    const float* Wv       = (const float*)d_in[8];
    const float* bv       = (const float*)d_in[9];
    const float* Wo       = (const float*)d_in[10];
    const float* bo       = (const float*)d_in[11];
    const float* rel_bias = (const float*)d_in[12];
    const float* W1       = (const float*)d_in[13];
    const float* b1       = (const float*)d_in[14];
    const float* W2       = (const float*)d_in[15];
    const float* b2       = (const float*)d_in[16];
    const float* g1       = (const float*)d_in[17];
    const float* be1      = (const float*)d_in[18];
    const float* g2       = (const float*)d_in[19];
    const float* be2      = (const float*)d_in[20];
    const float* gf       = (const float*)d_in[21];
    const float* bef      = (const float*)d_in[22];

    // ---- workspace layout (tight, liveness-based unions; total ≈ 63 MB) ----
    // residual xbuf now bf16 (halves residual-stream HBM traffic).
    char* ws = (char*)d_ws;
    u16* xbuf   = (u16*)ws;            ws += (size_t)MROWS * DMODEL * 2;   // 8.39MB residual bf16
    u16* hbuf   = (u16*)ws;            ws += (size_t)MROWS * DMODEL * 2;   // 8.39MB LN-out / attn-out
    u16* aobuf  = hbuf;                                                    // alias (time-shared)
    u16* qbf    = (u16*)ws;            ws += (size_t)MROWS * FF_DIM * 2;   // 32MB union region
    u16* kbf    = qbf + (size_t)MROWS * DMODEL;
    u16* vtbf   = kbf + (size_t)MROWS * DMODEL;
    u16* tbuf   = qbf;                 // FFN mid (32MB) reuses q/k/vt region
    u16* inbf   = qbf;                 // bf16 inputs (4.2MB), dead before qkv writes
    u16* wt_in  = (u16*)ws;            ws += (size_t)DMODEL * IN_DIM * 2;
    u16 *qkvw[2], *wto[2], *wt1[2], *wt2[2];
    for (int l = 0; l < 2; l++) { qkvw[l] = (u16*)ws; ws += (size_t)3 * DMODEL * DMODEL * 2; }
    for (int l = 0; l < 2; l++) { wto[l] = (u16*)ws; ws += (size_t)DMODEL * DMODEL * 2; }
    for (int l = 0; l < 2; l++) { wt1[l] = (u16*)ws; ws += (size_t)FF_DIM * DMODEL * 2; }
    for (int l = 0; l < 2; l++) { wt2[l] = (u16*)ws; ws += (size_t)DMODEL * FF_DIM * 2; }

    TArgs ta;
    int ti = 0, acct = 0;
    auto add = [&](const float* s, u16* d, int K, int N) {
        ta.d[ti] = {s, d, K, N};
        ta.start[ti] = acct;
        int tn = N / 32;
        int l2 = 31 - __builtin_clz((unsigned)tn);
        ta.l2tn[ti] = l2;
        acct += (K / 32) * tn;
        ti++;
    };
    add(W_in, wt_in, IN_DIM, DMODEL);
    for (int l = 0; l < 2; l++) {
        add(Wq + (size_t)l * DMODEL * DMODEL, qkvw[l], DMODEL, DMODEL);
        add(Wk + (size_t)l * DMODEL * DMODEL, qkvw[l] + (size_t)DMODEL * DMODEL, DMODEL, DMODEL);
        add(Wv + (size_t)l * DMODEL * DMODEL, qkvw[l] + (size_t)2 * DMODEL * DMODEL, DMODEL, DMODEL);
        add(Wo + (size_t)l * DMODEL * DMODEL, wto[l], DMODEL, DMODEL);
        add(W1 + (size_t)l * DMODEL * FF_DIM, wt1[l], DMODEL, FF_DIM);
        add(W2 + (size_t)l * FF_DIM * DMODEL, wt2[l], FF_DIM, DMODEL);
    }
    ta.start[13] = acct;

    conv_bf16_kernel<<<dim3((MROWS * IN_DIM / 4 + 255) / 256), 256, 0, stream>>>(
        inputs, inbf, MROWS * IN_DIM / 4);
    transpose_conv_kernel<<<dim3(acct), dim3(32, 8), 0, stream>>>(ta);

    gemm_in_kernel<<<dim3(DMODEL / 64, MROWS / 128), 256, 0, stream>>>(
        inbf, wt_in, b_in, xbuf, IN_DIM);

    for (int l = 0; l < 2; l++) {
        ln_kernel<true><<<MROWS / 4, 256, 0, stream>>>(xbuf, g1 + l * DMODEL, be1 + l * DMODEL, hbuf);
        gemm_qkv_kernel<<<dim3(3 * DMODEL / 128, MROWS / 128), 256, 0, stream>>>(
            hbuf, qkvw[l], bq + l * DMODEL, bk + l * DMODEL, bv + l * DMODEL,
            qbf, kbf, vtbf, DMODEL);
        fattn_kernel<<<dim3(512), 256, 0, stream>>>(
            qbf, kbf, vtbf, rel_bias + (size_t)l * NHEAD * 127, lengths, aobuf);
        gemm_res_kernel<<<dim3(DMODEL / 64, MROWS / 128), 256, 0, stream>>>(
            aobuf, wto[l], bo + l * DMODEL, xbuf, DMODEL);
        ln_kernel<true><<<MROWS / 4, 256, 0, stream>>>(xbuf, g2 + l * DMODEL, be2 + l * DMODEL, hbuf);
        gemm_relu_kernel<<<dim3(FF_DIM / 128, MROWS / 128), 256, 0, stream>>>(
            hbuf, wt1[l], b1 + l * FF_DIM, tbuf, FF_DIM, DMODEL);
        gemm_res_kernel<<<dim3(DMODEL / 64, MROWS / 128), 256, 0, stream>>>(
            tbuf, wt2[l], b2 + l * DMODEL, xbuf, FF_DIM);
    }
    ln_kernel<false><<<MROWS / 4, 256, 0, stream>>>(xbuf, gf, bef, d_out);
}

// Round 10
// 419.976 us; speedup vs baseline: 1.0864x; 1.0449x over previous
//
#include <hip/hip_runtime.h>
#include <hip/hip_bf16.h>

typedef unsigned short u16;
typedef unsigned int u32;
typedef __bf16 v8bf __attribute__((ext_vector_type(8)));
typedef float v4f __attribute__((ext_vector_type(4)));

#define B_SZ 8
#define S_LEN 1024
#define IN_DIM 256
#define DMODEL 512
#define NHEAD 8
#define DK 64
#define FF_DIM 2048
#define MROWS (B_SZ * S_LEN)   // 8192
#define QSCALE 0.1803368801111204f   // 0.125 * log2(e)

__device__ __forceinline__ u16 f2bf(float f) {
    unsigned int x = __float_as_uint(f);
    unsigned int r = (x + 0x7fffu + ((x >> 16) & 1u)) >> 16;
    return (u16)r;
}
__device__ __forceinline__ float bf2f(u16 v) {
    return __uint_as_float((u32)v << 16);
}

// async global->LDS DMA, 16B per lane; lds dest is wave-uniform base + lane*16
__device__ __forceinline__ void gl16(const u16* g, u16* l) {
    __builtin_amdgcn_global_load_lds((const __attribute__((address_space(1))) unsigned int*)g,
                                     (__attribute__((address_space(3))) unsigned int*)l, 16, 0, 0);
}

// XCD-chunked bijective grid swizzle (T1): 1-D grid (multiple of 8); XCD x owns a
// contiguous band of by rows across all bx -> A-panels fetched once per XCD L2.
__device__ __forceinline__ void swz_grid(int nbx, int& bx, int& by) {
    int bid = blockIdx.x;
    int chunk = gridDim.x >> 3;
    int wg = (bid & 7) * chunk + (bid >> 3);
    bx = wg % nbx;
    by = wg / nbx;
}

// ---------------- elementwise f32 -> bf16 (inputs matrix) ----------------
__global__ __launch_bounds__(256) void conv_bf16_kernel(const float* __restrict__ in,
                                                        u16* __restrict__ out, int n4) {
    int i = blockIdx.x * 256 + threadIdx.x;
    if (i < n4) {
        float4 v = ((const float4*)in)[i];
        ushort4 o;
        o.x = f2bf(v.x); o.y = f2bf(v.y); o.z = f2bf(v.z); o.w = f2bf(v.w);
        ((ushort4*)out)[i] = o;
    }
}

// ------------- batched transpose+convert: (K,N) f32 -> (N,K) bf16 -------------
struct TDesc { const float* src; u16* dst; int K; int N; };
struct TArgs { TDesc d[13]; int start[14]; int l2tn[13]; };

__global__ void transpose_conv_kernel(TArgs args) {
    int bid = blockIdx.x;
    int z = 0;
    while (z < 12 && bid >= args.start[z + 1]) z++;
    TDesc t = args.d[z];
    int local = bid - args.start[z];
    int l2 = args.l2tn[z];
    int k0 = (local >> l2) << 5;
    int n0 = (local & ((1 << l2) - 1)) << 5;
    __shared__ float tile[32][33];
    int tx = threadIdx.x, ty = threadIdx.y;
#pragma unroll
    for (int j = 0; j < 4; j++) {
        int k = k0 + ty + j * 8;
        tile[ty + j * 8][tx] = t.src[(size_t)k * t.N + n0 + tx];
    }
    __syncthreads();
#pragma unroll
    for (int j = 0; j < 4; j++) {
        int n = n0 + ty + j * 8;
        t.dst[(size_t)n * t.K + k0 + tx] = f2bf(tile[tx][ty + j * 8]);
    }
}

// ------- LayerNorm: bf16 residual in -> bf16 (or fp32) out -------
template <bool OUT_BF16>
__global__ __launch_bounds__(256) void ln_kernel(const u16* __restrict__ x,
                                                 const float* __restrict__ g,
                                                 const float* __restrict__ b,
                                                 void* __restrict__ out) {
    int row = blockIdx.x * 4 + (threadIdx.x >> 6);
    int lane = threadIdx.x & 63;
    uint4 v = ((const uint4*)(x + (size_t)row * DMODEL))[lane];
    float f[8];
    f[0] = __uint_as_float(v.x << 16); f[1] = __uint_as_float(v.x & 0xffff0000u);
    f[2] = __uint_as_float(v.y << 16); f[3] = __uint_as_float(v.y & 0xffff0000u);
    f[4] = __uint_as_float(v.z << 16); f[5] = __uint_as_float(v.z & 0xffff0000u);
    f[6] = __uint_as_float(v.w << 16); f[7] = __uint_as_float(v.w & 0xffff0000u);
    float s = 0.f, sq = 0.f;
#pragma unroll
    for (int i = 0; i < 8; i++) { s += f[i]; sq += f[i] * f[i]; }
#pragma unroll
    for (int m = 1; m < 64; m <<= 1) {
        s += __shfl_xor(s, m);
        sq += __shfl_xor(sq, m);
    }
    float mean = s * (1.0f / DMODEL);
    float var = sq * (1.0f / DMODEL) - mean * mean;
    float rstd = rsqrtf(var + 1e-5f);
    const float4* g4 = (const float4*)g;
    const float4* b4 = (const float4*)b;
    float4 ga = g4[lane * 2], gb = g4[lane * 2 + 1];
    float4 ba = b4[lane * 2], bb = b4[lane * 2 + 1];
    float r[8];
    r[0] = (f[0] - mean) * rstd * ga.x + ba.x;
    r[1] = (f[1] - mean) * rstd * ga.y + ba.y;
    r[2] = (f[2] - mean) * rstd * ga.z + ba.z;
    r[3] = (f[3] - mean) * rstd * ga.w + ba.w;
    r[4] = (f[4] - mean) * rstd * gb.x + bb.x;
    r[5] = (f[5] - mean) * rstd * gb.y + bb.y;
    r[6] = (f[6] - mean) * rstd * gb.z + bb.z;
    r[7] = (f[7] - mean) * rstd * gb.w + bb.w;
    if (OUT_BF16) {
        uint4 o;
        o.x = (u32)f2bf(r[0]) | ((u32)f2bf(r[1]) << 16);
        o.y = (u32)f2bf(r[2]) | ((u32)f2bf(r[3]) << 16);
        o.z = (u32)f2bf(r[4]) | ((u32)f2bf(r[5]) << 16);
        o.w = (u32)f2bf(r[6]) | ((u32)f2bf(r[7]) << 16);
        ((uint4*)out)[(size_t)row * 64 + lane] = o;
    } else {
        float4 o0 = {r[0], r[1], r[2], r[3]};
        float4 o1 = {r[4], r[5], r[6], r[7]};
        ((float4*)out)[(size_t)row * 128 + lane * 2] = o0;
        ((float4*)out)[(size_t)row * 128 + lane * 2 + 1] = o1;
    }
}

// ------- shared GEMM core: (MT*32) x (NT*32) tile, BK=64, XOR-swizzled LDS -------
// (r7 known-best structure; takes swizzled tile origin m0/n0)
template <int MT, int NT>
__device__ __forceinline__ void gemm_core(const u16* __restrict__ A, const u16* __restrict__ Bt,
                                          int K, int m0, int n0, v4f (&acc)[MT][NT]) {
    constexpr int BM = MT * 32;
    constexpr int BN = NT * 32;
    __shared__ u16 As[BM * 64];
    __shared__ u16 Bs[BN * 64];
    int tid = threadIdx.x;
    int w = tid >> 6, lane = tid & 63;
    int wr = (w >> 1) * (BM / 2), wc = (w & 1) * (BN / 2);
    int lr = lane & 15, lq = lane >> 4;
    int r8 = lane >> 3, cb = lane & 7;
    int scol = (cb ^ r8) * 8;

    v4f zero = {0.f, 0.f, 0.f, 0.f};
#pragma unroll
    for (int i = 0; i < MT; i++)
#pragma unroll
        for (int j = 0; j < NT; j++) acc[i][j] = zero;

    const u16* gA[MT]; u16* lA[MT];
#pragma unroll
    for (int j = 0; j < MT; j++) {
        int row0 = (MT * 8) * w + j * 8;
        gA[j] = A + (size_t)(m0 + row0 + r8) * K + scol;
        lA[j] = As + row0 * 64;
    }
    const u16* gB[NT]; u16* lB[NT];
#pragma unroll
    for (int j = 0; j < NT; j++) {
        int row0 = (NT * 8) * w + j * 8;
        gB[j] = Bt + (size_t)(n0 + row0 + r8) * K + scol;
        lB[j] = Bs + row0 * 64;
    }

    for (int k0 = 0; k0 < K; k0 += 64) {
#pragma unroll
        for (int j = 0; j < MT; j++) gl16(gA[j], lA[j]);
#pragma unroll
        for (int j = 0; j < NT; j++) gl16(gB[j], lB[j]);
        __syncthreads();   // vmcnt drain -> tiles ready
#pragma unroll
        for (int kk = 0; kk < 2; kk++) {
            int xb = ((kk * 4 + lq) ^ (lr & 7)) * 8;
            v8bf af[MT], bfr[NT];
#pragma unroll
            for (int i = 0; i < MT; i++)
                af[i] = *(const v8bf*)&As[(wr + i * 16 + lr) * 64 + xb];
#pragma unroll
            for (int j = 0; j < NT; j++)
                bfr[j] = *(const v8bf*)&Bs[(wc + j * 16 + lr) * 64 + xb];
#pragma unroll
            for (int mt = 0; mt < MT; mt++)
#pragma unroll
                for (int nt = 0; nt < NT; nt++)
                    acc[mt][nt] = __builtin_amdgcn_mfma_f32_16x16x32_bf16(af[mt], bfr[nt], acc[mt][nt], 0, 0, 0);
        }
        __syncthreads();   // frag reads done before next DMA overwrites
#pragma unroll
        for (int j = 0; j < MT; j++) gA[j] += 64;
#pragma unroll
        for (int j = 0; j < NT; j++) gB[j] += 64;
    }
}

// ---- input projection: bf16 residual out + bias + sinusoid PE (N=512, 128x64) ----
__global__ __launch_bounds__(256) void gemm_in_kernel(const u16* __restrict__ A,
                                                      const u16* __restrict__ Bt,
                                                      const float* __restrict__ bias,
                                                      u16* __restrict__ Out, int K) {
    int bx, by;
    swz_grid(8, bx, by);
    int n0 = bx * 64, m0 = by * 128;
    v4f acc[4][2];
    gemm_core<4, 2>(A, Bt, K, m0, n0, acc);
    int tid = threadIdx.x, w = tid >> 6, lane = tid & 63;
    int lr = lane & 15, lq = lane >> 4;
    int wr = (w >> 1) * 64, wc = (w & 1) * 32;
#pragma unroll
    for (int mt = 0; mt < 4; mt++) {
#pragma unroll
        for (int nt = 0; nt < 2; nt++) {
            int col = n0 + wc + nt * 16 + lr;
            float bcol = bias[col];
            float freq = __builtin_amdgcn_exp2f((float)(col & ~1) * (-0.025953277f));
#pragma unroll
            for (int reg = 0; reg < 4; reg++) {
                int row = m0 + wr + mt * 16 + lq * 4 + reg;
                float rev = (float)(row & (S_LEN - 1)) * freq * 0.15915494309189535f;
                float fr = __builtin_amdgcn_fractf(rev);
                float pe = (col & 1) ? __builtin_amdgcn_cosf(fr) : __builtin_amdgcn_sinf(fr);
                Out[(size_t)row * DMODEL + col] = f2bf(acc[mt][nt][reg] + bcol + pe);
            }
        }
    }
}

// ---- fused QKV projection: N=1536 (128x128); segment block-uniform ----
__global__ __launch_bounds__(256) void gemm_qkv_kernel(const u16* __restrict__ A,
                                                       const u16* __restrict__ Bt,
                                                       const float* __restrict__ bq,
                                                       const float* __restrict__ bk,
                                                       const float* __restrict__ bv,
                                                       u16* __restrict__ Qo,
                                                       u16* __restrict__ Ko,
                                                       u16* __restrict__ Vto, int K) {
    int bx, by;
    swz_grid(12, bx, by);
    int n0 = bx * 128, m0 = by * 128;
    v4f acc[4][4];
    gemm_core<4, 4>(A, Bt, K, m0, n0, acc);
    int tid = threadIdx.x, w = tid >> 6, lane = tid & 63;
    int lr = lane & 15, lq = lane >> 4;
    int wr = (w >> 1) * 64, wc = (w & 1) * 64;
    int seg = n0 >> 9;
#pragma unroll
    for (int mt = 0; mt < 4; mt++) {
#pragma unroll
        for (int nt = 0; nt < 4; nt++) {
            int col = (n0 + wc + nt * 16 + lr) & (DMODEL - 1);
            if (seg == 0) {
                float bcol = bq[col];
#pragma unroll
                for (int reg = 0; reg < 4; reg++) {
                    int row = m0 + wr + mt * 16 + lq * 4 + reg;
                    Qo[(size_t)row * DMODEL + col] = f2bf((acc[mt][nt][reg] + bcol) * QSCALE);
                }
            } else if (seg == 1) {
                float bcol = bk[col];
#pragma unroll
                for (int reg = 0; reg < 4; reg++) {
                    int row = m0 + wr + mt * 16 + lq * 4 + reg;
                    Ko[(size_t)row * DMODEL + col] = f2bf(acc[mt][nt][reg] + bcol);
                }
            } else {
                float bcol = bv[col];
                int row0 = m0 + wr + mt * 16 + lq * 4;
                int bb = row0 >> 10, s0 = row0 & (S_LEN - 1);
                ushort4 o;
                o.x = f2bf(acc[mt][nt][0] + bcol);
                o.y = f2bf(acc[mt][nt][1] + bcol);
                o.z = f2bf(acc[mt][nt][2] + bcol);
                o.w = f2bf(acc[mt][nt][3] + bcol);
                *(ushort4*)(Vto + ((size_t)(bb * DMODEL + col)) * S_LEN + s0) = o;
            }
        }
    }
}

// ---- FFN1: bf16 out + bias + ReLU (N=2048, 128x128 tile) ----
__global__ __launch_bounds__(256) void gemm_relu_kernel(const u16* __restrict__ A,
                                                        const u16* __restrict__ Bt,
                                                        const float* __restrict__ bias,
                                                        u16* __restrict__ Out, int N, int K) {
    int bx, by;
    swz_grid(N >> 7, bx, by);
    int n0 = bx * 128, m0 = by * 128;
    v4f acc[4][4];
    gemm_core<4, 4>(A, Bt, K, m0, n0, acc);
    int tid = threadIdx.x, w = tid >> 6, lane = tid & 63;
    int lr = lane & 15, lq = lane >> 4;
    int wr = (w >> 1) * 64, wc = (w & 1) * 64;
#pragma unroll
    for (int mt = 0; mt < 4; mt++) {
#pragma unroll
        for (int nt = 0; nt < 4; nt++) {
            int col = n0 + wc + nt * 16 + lr;
            float bcol = bias[col];
#pragma unroll
            for (int reg = 0; reg < 4; reg++) {
                int row = m0 + wr + mt * 16 + lq * 4 + reg;
                Out[(size_t)row * N + col] = f2bf(fmaxf(acc[mt][nt][reg] + bcol, 0.0f));
            }
        }
    }
}

// ---- O-proj / FFN2: bf16 residual RMW + bias (N=512, 128x64) ----
__global__ __launch_bounds__(256) void gemm_res_kernel(const u16* __restrict__ A,
                                                       const u16* __restrict__ Bt,
                                                       const float* __restrict__ bias,
                                                       u16* __restrict__ Out, int K) {
    int bx, by;
    swz_grid(8, bx, by);
    int n0 = bx * 64, m0 = by * 128;
    v4f acc[4][2];
    gemm_core<4, 2>(A, Bt, K, m0, n0, acc);
    int tid = threadIdx.x, w = tid >> 6, lane = tid & 63;
    int lr = lane & 15, lq = lane >> 4;
    int wr = (w >> 1) * 64, wc = (w & 1) * 32;
#pragma unroll
    for (int mt = 0; mt < 4; mt++) {
#pragma unroll
        for (int nt = 0; nt < 2; nt++) {
            int col = n0 + wc + nt * 16 + lr;
            float bcol = bias[col];
#pragma unroll
            for (int reg = 0; reg < 4; reg++) {
                int row = m0 + wr + mt * 16 + lq * 4 + reg;
                size_t idx = (size_t)row * DMODEL + col;
                Out[idx] = f2bf(bf2f(Out[idx]) + acc[mt][nt][reg] + bcol);
            }
        }
    }
}

// -------- MFMA flash attention v11: no split-K, in-register P, counted-vmcnt pipeline --------
__global__ __launch_bounds__(256, 4) void fattn_kernel(const u16* __restrict__ Qg,
                                                       const u16* __restrict__ Kg,
                                                       const u16* __restrict__ Vtg,
                                                       const float* __restrict__ rb,
                                                       const int* __restrict__ lengths,
                                                       u16* __restrict__ O) {
    int bid = blockIdx.x;
    int wg = (bid & 7) * 64 + (bid >> 3);
    int i = wg & 63;
    int h = wg >> 6;            // XCD-local head
    int b = i & 7;              // interleaved batch -> len-balanced CUs
    int qt = (i >> 3) & 7;
    int tid = threadIdx.x, w = tid >> 6, lane = tid & 63;
    int lr = lane & 15, lq = lane >> 4;
    __shared__ u16 Ks[3][64 * 64];
    __shared__ u16 Vs[3][64 * 64];
    __shared__ float rbs[128];
    int len = lengths[b];
    if (tid < 127) rbs[tid] = rb[h * 127 + tid] * 1.4426950408889634f;  // fold log2(e)

    int nchunks = (len + 63) >> 6;   // >= 8 (len >= 512)

    int qw = qt * 128 + w * 32;   // wave's 32 q rows
    v8bf qa[2][2];                // B-operand: rows q = qw + ntq*16 + lr
#pragma unroll
    for (int ntq = 0; ntq < 2; ntq++) {
        size_t qrow = ((size_t)(b * S_LEN + qw + ntq * 16 + lr)) * DMODEL + h * DK;
        qa[ntq][0] = *(const v8bf*)(Qg + qrow + lq * 8);
        qa[ntq][1] = *(const v8bf*)(Qg + qrow + 32 + lq * 8);
    }

    v4f zero = {0.f, 0.f, 0.f, 0.f};
    v4f Oacc[4][2];   // [dtile][ntq]: O^T -> lane holds q=lr col, d=dt*16+lq*4+r rows
#pragma unroll
    for (int dt = 0; dt < 4; dt++)
#pragma unroll
        for (int nt = 0; nt < 2; nt++) Oacc[dt][nt] = zero;
    float lsum[2] = {0.f, 0.f};

    const u16* Kbase = Kg + ((size_t)b * S_LEN) * DMODEL + h * DK;
    const u16* Vbase = Vtg + ((size_t)(b * DMODEL + h * DK)) * S_LEN;
    int r8 = lane >> 3, cb = lane & 7;
    int swz = (cb ^ r8) * 8;

    // prologue: DMA chunks 0,1 into buffers 0,1 (nchunks >= 8)
#pragma unroll
    for (int j = 0; j < 2; j++) {
        int row0 = w * 16 + j * 8;
        gl16(Kbase + (size_t)(row0 + r8) * DMODEL + swz, Ks[0] + row0 * 64);
        gl16(Vbase + (size_t)(row0 + r8) * S_LEN + swz, Vs[0] + row0 * 64);
    }
#pragma unroll
    for (int j = 0; j < 2; j++) {
        int row0 = w * 16 + j * 8;
        gl16(Kbase + (size_t)(64 + row0 + r8) * DMODEL + swz, Ks[1] + row0 * 64);
        gl16(Vbase + (size_t)(row0 + r8) * S_LEN + 64 + swz, Vs[1] + row0 * 64);
    }
    __syncthreads();   // one-time full drain: c0,c1 + rbs staged and visible

    u16 *KsA = Ks[0], *VsA = Vs[0];   // current compute buffer
    u16 *KsB = Ks[1], *VsB = Vs[1];   // next (in flight or landed)
    u16 *KsC = Ks[2], *VsC = Vs[2];   // landing slot for c(i+2)

    for (int ci = 0; ci < nchunks; ci++) {
        int kb0 = ci * 64;
        if (ci > 0) {
            if (ci + 1 < nchunks) asm volatile("s_waitcnt vmcnt(4)" ::: "memory");
            else                  asm volatile("s_waitcnt vmcnt(0)" ::: "memory");
            __builtin_amdgcn_s_barrier();        // all waves: buf A ready; compute c(ci-1) done
            __builtin_amdgcn_sched_barrier(0);   // pin issue below the barrier
        }
        if (ci + 2 < nchunks) {   // issue c(ci+2) into C (overwrites c(ci-1)'s buffer, now safe)
            int nk = kb0 + 128;
#pragma unroll
            for (int j = 0; j < 2; j++) {
                int row0 = w * 16 + j * 8;
                gl16(Kbase + (size_t)(nk + row0 + r8) * DMODEL + swz, KsC + row0 * 64);
                gl16(Vbase + (size_t)(row0 + r8) * S_LEN + nk + swz, VsC + row0 * 64);
            }
        }
        const u16* Ksc = KsA;
        const u16* Vsc = VsA;

        // S^T = K @ Q^T : lane holds key = kb0+mtk*16+lq*4+r (rows), q = qw+ntq*16+lr (cols)
        v4f S[4][2];
        __builtin_amdgcn_s_setprio(1);
#pragma unroll
        for (int mtk = 0; mtk < 4; mtk++) {
            int xb0 = (lq ^ (lr & 7)) * 8;
            int xb1 = ((4 + lq) ^ (lr & 7)) * 8;
            v8bf kf0 = *(const v8bf*)&Ksc[(mtk * 16 + lr) * 64 + xb0];
            v8bf kf1 = *(const v8bf*)&Ksc[(mtk * 16 + lr) * 64 + xb1];
#pragma unroll
            for (int ntq = 0; ntq < 2; ntq++) {
                v4f s = __builtin_amdgcn_mfma_f32_16x16x32_bf16(kf0, qa[ntq][0], zero, 0, 0, 0);
                S[mtk][ntq] = __builtin_amdgcn_mfma_f32_16x16x32_bf16(kf1, qa[ntq][1], s, 0, 0, 0);
            }
        }
        __builtin_amdgcn_s_setprio(0);

        bool edge = (kb0 + 64 > len);
        int dmin = qw - (kb0 + 63), dmax = qw + 31 - kb0;
        bool perel = !(dmax <= -63 || dmin >= 63);
        float bconst = (dmax <= -63) ? rbs[0] : rbs[126];
        uint2 pks[4][2];   // packed bf16 P, lane-local (keys lq*4+r of tile mtk, q col lr)
#pragma unroll
        for (int mtk = 0; mtk < 4; mtk++) {
#pragma unroll
            for (int ntq = 0; ntq < 2; ntq++) {
                int q = qw + ntq * 16 + lr;
                float p[4];
#pragma unroll
                for (int r = 0; r < 4; r++) {
                    int key = kb0 + mtk * 16 + lq * 4 + r;
                    float s = S[mtk][ntq][r];
                    if (perel) {
                        int d = q - key;
                        d = d < -63 ? -63 : (d > 63 ? 63 : d);
                        s += rbs[d + 63];
                    } else {
                        s += bconst;
                    }
                    float pv = __builtin_amdgcn_exp2f(s);
                    if (edge && key >= len) pv = 0.f;
                    lsum[ntq] += pv;
                    p[r] = pv;
                }
                // truncating bf16 pack: relative bias cancels in normalization
                pks[mtk][ntq].x = (__float_as_uint(p[1]) & 0xffff0000u) | (__float_as_uint(p[0]) >> 16);
                pks[mtk][ntq].y = (__float_as_uint(p[3]) & 0xffff0000u) | (__float_as_uint(p[2]) >> 16);
            }
        }

        // O^T += V^T @ P^T with permuted k-order: k=lq*8+j <-> key = kh*32 + (j<4 ? lq*4+j
        // : 16+lq*4+j-4). B-frag = lane's own pks; A-frag = two swizzled b64 reads from Vs.
        __builtin_amdgcn_s_setprio(1);
#pragma unroll
        for (int kh = 0; kh < 2; kh++) {
            uint4 tp0 = {pks[kh * 2][0].x, pks[kh * 2][0].y, pks[kh * 2 + 1][0].x, pks[kh * 2 + 1][0].y};
            uint4 tp1 = {pks[kh * 2][1].x, pks[kh * 2][1].y, pks[kh * 2 + 1][1].x, pks[kh * 2 + 1][1].y};
            v8bf pb0 = *(v8bf*)&tp0;
            v8bf pb1 = *(v8bf*)&tp1;
            int gl = kh * 4 + (lq >> 1);
            int sub = (lq & 1) * 4;
#pragma unroll
            for (int dt = 0; dt < 4; dt++) {
                int drow = (dt * 16 + lr) * 64;
                uint2 lo = *(const uint2*)&Vsc[drow + ((gl ^ (lr & 7)) * 8 + sub)];
                uint2 hi = *(const uint2*)&Vsc[drow + (((gl + 2) ^ (lr & 7)) * 8 + sub)];
                uint4 tv = {lo.x, lo.y, hi.x, hi.y};
                v8bf va = *(v8bf*)&tv;
                Oacc[dt][0] = __builtin_amdgcn_mfma_f32_16x16x32_bf16(va, pb0, Oacc[dt][0], 0, 0, 0);
                Oacc[dt][1] = __builtin_amdgcn_mfma_f32_16x16x32_bf16(va, pb1, Oacc[dt][1], 0, 0, 0);
            }
        }
        __builtin_amdgcn_s_setprio(0);

        // rotate buffers: A <- B <- C <- A
        u16* t;
        t = KsA; KsA = KsB; KsB = KsC; KsC = t;
        t = VsA; VsA = VsB; VsB = VsC; VsC = t;
    }

    // reduce row sums across key quads (lane then holds total for q = qw+ntq*16+lr)
    float inv[2];
#pragma unroll
    for (int ntq = 0; ntq < 2; ntq++) {
        float s = lsum[ntq];
        s += __shfl_xor(s, 16);
        s += __shfl_xor(s, 32);
        inv[ntq] = 1.0f / s;
    }
    // normalized O (bf16): lane writes 4 consecutive d per tile -> 8B stores
#pragma unroll
    for (int dt = 0; dt < 4; dt++) {
#pragma unroll
        for (int ntq = 0; ntq < 2; ntq++) {
            size_t off = (size_t)(b * S_LEN + qw + ntq * 16 + lr) * DMODEL + h * DK + dt * 16 + lq * 4;
            ushort4 o;
            o.x = f2bf(Oacc[dt][ntq][0] * inv[ntq]);
            o.y = f2bf(Oacc[dt][ntq][1] * inv[ntq]);
            o.z = f2bf(Oacc[dt][ntq][2] * inv[ntq]);
            o.w = f2bf(Oacc[dt][ntq][3] * inv[ntq]);
            *(ushort4*)(O + off) = o;
        }
    }
}

extern "C" void kernel_launch(void* const* d_in, const int* in_sizes, int n_in,
                              void* d_out, int out_size, void* d_ws, size_t ws_size,
                              hipStream_t stream) {
    const float* inputs   = (const float*)d_in[0];
    const int*   lengths  = (const int*)d_in[1];
    const float* W_in     = (const float*)d_in[2];
    const float* b_in     = (const float*)d_in[3];
    const float* Wq       = (const float*)d_in[4];
    const float* bq       = (const float*)d_in[5];
    const float* Wk       = (const float*)d_in[6];
    const float* bk       = (const float*)d_in[7];
    const float* Wv       = (const float*)d_in[8];
    const float* bv       = (const float*)d_in[9];
    const float* Wo       = (const float*)d_in[10];
    const float* bo       = (const float*)d_in[11];
    const float* rel_bias = (const float*)d_in[12];
    const float* W1       = (const float*)d_in[13];
    const float* b1       = (const float*)d_in[14];
    const float* W2       = (const float*)d_in[15];
    const float* b2       = (const float*)d_in[16];
    const float* g1       = (const float*)d_in[17];
    const float* be1      = (const float*)d_in[18];
    const float* g2       = (const float*)d_in[19];
    const float* be2      = (const float*)d_in[20];
    const float* gf       = (const float*)d_in[21];
    const float* bef      = (const float*)d_in[22];

    // ---- workspace layout (tight, liveness-based unions; total ≈ 63 MB) ----
    char* ws = (char*)d_ws;
    u16* xbuf   = (u16*)ws;            ws += (size_t)MROWS * DMODEL * 2;   // 8.39MB residual bf16
    u16* hbuf   = (u16*)ws;            ws += (size_t)MROWS * DMODEL * 2;   // 8.39MB LN-out / attn-out
    u16* aobuf  = hbuf;                                                    // alias (time-shared)
    u16* qbf    = (u16*)ws;            ws += (size_t)MROWS * FF_DIM * 2;   // 32MB union region
    u16* kbf    = qbf + (size_t)MROWS * DMODEL;
    u16* vtbf   = kbf + (size_t)MROWS * DMODEL;
    u16* tbuf   = qbf;                 // FFN mid (32MB) reuses q/k/vt region
    u16* inbf   = qbf;                 // bf16 inputs (4.2MB), dead before qkv writes
    u16* wt_in  = (u16*)ws;            ws += (size_t)DMODEL * IN_DIM * 2;
    u16 *qkvw[2], *wto[2], *wt1[2], *wt2[2];
    for (int l = 0; l < 2; l++) { qkvw[l] = (u16*)ws; ws += (size_t)3 * DMODEL * DMODEL * 2; }
    for (int l = 0; l < 2; l++) { wto[l] = (u16*)ws; ws += (size_t)DMODEL * DMODEL * 2; }
    for (int l = 0; l < 2; l++) { wt1[l] = (u16*)ws; ws += (size_t)FF_DIM * DMODEL * 2; }
    for (int l = 0; l < 2; l++) { wt2[l] = (u16*)ws; ws += (size_t)DMODEL * FF_DIM * 2; }

    TArgs ta;
    int ti = 0, acct = 0;
    auto add = [&](const float* s, u16* d, int K, int N) {
        ta.d[ti] = {s, d, K, N};
        ta.start[ti] = acct;
        int tn = N / 32;
        int l2 = 31 - __builtin_clz((unsigned)tn);
        ta.l2tn[ti] = l2;
        acct += (K / 32) * tn;
        ti++;
    };
    add(W_in, wt_in, IN_DIM, DMODEL);
    for (int l = 0; l < 2; l++) {
        add(Wq + (size_t)l * DMODEL * DMODEL, qkvw[l], DMODEL, DMODEL);
        add(Wk + (size_t)l * DMODEL * DMODEL, qkvw[l] + (size_t)DMODEL * DMODEL, DMODEL, DMODEL);
        add(Wv + (size_t)l * DMODEL * DMODEL, qkvw[l] + (size_t)2 * DMODEL * DMODEL, DMODEL, DMODEL);
        add(Wo + (size_t)l * DMODEL * DMODEL, wto[l], DMODEL, DMODEL);
        add(W1 + (size_t)l * DMODEL * FF_DIM, wt1[l], DMODEL, FF_DIM);
        add(W2 + (size_t)l * FF_DIM * DMODEL, wt2[l], FF_DIM, DMODEL);
    }
    ta.start[13] = acct;

    conv_bf16_kernel<<<dim3((MROWS * IN_DIM / 4 + 255) / 256), 256, 0, stream>>>(
        inputs, inbf, MROWS * IN_DIM / 4);
    transpose_conv_kernel<<<dim3(acct), dim3(32, 8), 0, stream>>>(ta);

    gemm_in_kernel<<<dim3(512), 256, 0, stream>>>(
        inbf, wt_in, b_in, xbuf, IN_DIM);

    for (int l = 0; l < 2; l++) {
        ln_kernel<true><<<MROWS / 4, 256, 0, stream>>>(xbuf, g1 + l * DMODEL, be1 + l * DMODEL, hbuf);
        gemm_qkv_kernel<<<dim3(768), 256, 0, stream>>>(
            hbuf, qkvw[l], bq + l * DMODEL, bk + l * DMODEL, bv + l * DMODEL,
            qbf, kbf, vtbf, DMODEL);
        fattn_kernel<<<dim3(512), 256, 0, stream>>>(
            qbf, kbf, vtbf, rel_bias + (size_t)l * NHEAD * 127, lengths, aobuf);
        gemm_res_kernel<<<dim3(512), 256, 0, stream>>>(
            aobuf, wto[l], bo + l * DMODEL, xbuf, DMODEL);
        ln_kernel<true><<<MROWS / 4, 256, 0, stream>>>(xbuf, g2 + l * DMODEL, be2 + l * DMODEL, hbuf);
        gemm_relu_kernel<<<dim3(1024), 256, 0, stream>>>(
            hbuf, wt1[l], b1 + l * FF_DIM, tbuf, FF_DIM, DMODEL);
        gemm_res_kernel<<<dim3(512), 256, 0, stream>>>(
            tbuf, wt2[l], b2 + l * DMODEL, xbuf, FF_DIM);
    }
    ln_kernel<false><<<MROWS / 4, 256, 0, stream>>>(xbuf, gf, bef, d_out);
}

// Round 11
// 397.925 us; speedup vs baseline: 1.1466x; 1.0554x over previous
//
#include <hip/hip_runtime.h>
#include <hip/hip_bf16.h>

typedef unsigned short u16;
typedef unsigned int u32;
typedef __bf16 v8bf __attribute__((ext_vector_type(8)));
typedef float v4f __attribute__((ext_vector_type(4)));

#define B_SZ 8
#define S_LEN 1024
#define IN_DIM 256
#define DMODEL 512
#define NHEAD 8
#define DK 64
#define FF_DIM 2048
#define MROWS (B_SZ * S_LEN)   // 8192
#define QSCALE 0.1803368801111204f   // 0.125 * log2(e)

__device__ __forceinline__ u16 f2bf(float f) {
    unsigned int x = __float_as_uint(f);
    unsigned int r = (x + 0x7fffu + ((x >> 16) & 1u)) >> 16;
    return (u16)r;
}
__device__ __forceinline__ float bf2f(u16 v) {
    return __uint_as_float((u32)v << 16);
}

// async global->LDS DMA, 16B per lane; lds dest is wave-uniform base + lane*16
__device__ __forceinline__ void gl16(const u16* g, u16* l) {
    __builtin_amdgcn_global_load_lds((const __attribute__((address_space(1))) unsigned int*)g,
                                     (__attribute__((address_space(3))) unsigned int*)l, 16, 0, 0);
}

// XCD-chunked bijective grid swizzle (T1): 1-D grid (multiple of 8); XCD x owns a
// contiguous band of by rows across all bx -> A-panels fetched once per XCD L2.
__device__ __forceinline__ void swz_grid(int nbx, int& bx, int& by) {
    int bid = blockIdx.x;
    int chunk = gridDim.x >> 3;
    int wg = (bid & 7) * chunk + (bid >> 3);
    bx = wg % nbx;
    by = wg / nbx;
}

// ---------------- elementwise f32 -> bf16 (inputs matrix) ----------------
__global__ __launch_bounds__(256) void conv_bf16_kernel(const float* __restrict__ in,
                                                        u16* __restrict__ out, int n4) {
    int i = blockIdx.x * 256 + threadIdx.x;
    if (i < n4) {
        float4 v = ((const float4*)in)[i];
        ushort4 o;
        o.x = f2bf(v.x); o.y = f2bf(v.y); o.z = f2bf(v.z); o.w = f2bf(v.w);
        ((ushort4*)out)[i] = o;
    }
}

// ------------- batched transpose+convert: (K,N) f32 -> (N,K) bf16 -------------
struct TDesc { const float* src; u16* dst; int K; int N; };
struct TArgs { TDesc d[13]; int start[14]; int l2tn[13]; };

__global__ void transpose_conv_kernel(TArgs args) {
    int bid = blockIdx.x;
    int z = 0;
    while (z < 12 && bid >= args.start[z + 1]) z++;
    TDesc t = args.d[z];
    int local = bid - args.start[z];
    int l2 = args.l2tn[z];
    int k0 = (local >> l2) << 5;
    int n0 = (local & ((1 << l2) - 1)) << 5;
    __shared__ float tile[32][33];
    int tx = threadIdx.x, ty = threadIdx.y;
#pragma unroll
    for (int j = 0; j < 4; j++) {
        int k = k0 + ty + j * 8;
        tile[ty + j * 8][tx] = t.src[(size_t)k * t.N + n0 + tx];
    }
    __syncthreads();
#pragma unroll
    for (int j = 0; j < 4; j++) {
        int n = n0 + ty + j * 8;
        t.dst[(size_t)n * t.K + k0 + tx] = f2bf(tile[tx][ty + j * 8]);
    }
}

// ------- LayerNorm: bf16 residual in -> bf16 (or fp32) out -------
template <bool OUT_BF16>
__global__ __launch_bounds__(256) void ln_kernel(const u16* __restrict__ x,
                                                 const float* __restrict__ g,
                                                 const float* __restrict__ b,
                                                 void* __restrict__ out) {
    int row = blockIdx.x * 4 + (threadIdx.x >> 6);
    int lane = threadIdx.x & 63;
    uint4 v = ((const uint4*)(x + (size_t)row * DMODEL))[lane];
    float f[8];
    f[0] = __uint_as_float(v.x << 16); f[1] = __uint_as_float(v.x & 0xffff0000u);
    f[2] = __uint_as_float(v.y << 16); f[3] = __uint_as_float(v.y & 0xffff0000u);
    f[4] = __uint_as_float(v.z << 16); f[5] = __uint_as_float(v.z & 0xffff0000u);
    f[6] = __uint_as_float(v.w << 16); f[7] = __uint_as_float(v.w & 0xffff0000u);
    float s = 0.f, sq = 0.f;
#pragma unroll
    for (int i = 0; i < 8; i++) { s += f[i]; sq += f[i] * f[i]; }
#pragma unroll
    for (int m = 1; m < 64; m <<= 1) {
        s += __shfl_xor(s, m);
        sq += __shfl_xor(sq, m);
    }
    float mean = s * (1.0f / DMODEL);
    float var = sq * (1.0f / DMODEL) - mean * mean;
    float rstd = rsqrtf(var + 1e-5f);
    const float4* g4 = (const float4*)g;
    const float4* b4 = (const float4*)b;
    float4 ga = g4[lane * 2], gb = g4[lane * 2 + 1];
    float4 ba = b4[lane * 2], bb = b4[lane * 2 + 1];
    float r[8];
    r[0] = (f[0] - mean) * rstd * ga.x + ba.x;
    r[1] = (f[1] - mean) * rstd * ga.y + ba.y;
    r[2] = (f[2] - mean) * rstd * ga.z + ba.z;
    r[3] = (f[3] - mean) * rstd * ga.w + ba.w;
    r[4] = (f[4] - mean) * rstd * gb.x + bb.x;
    r[5] = (f[5] - mean) * rstd * gb.y + bb.y;
    r[6] = (f[6] - mean) * rstd * gb.z + bb.z;
    r[7] = (f[7] - mean) * rstd * gb.w + bb.w;
    if (OUT_BF16) {
        uint4 o;
        o.x = (u32)f2bf(r[0]) | ((u32)f2bf(r[1]) << 16);
        o.y = (u32)f2bf(r[2]) | ((u32)f2bf(r[3]) << 16);
        o.z = (u32)f2bf(r[4]) | ((u32)f2bf(r[5]) << 16);
        o.w = (u32)f2bf(r[6]) | ((u32)f2bf(r[7]) << 16);
        ((uint4*)out)[(size_t)row * 64 + lane] = o;
    } else {
        float4 o0 = {r[0], r[1], r[2], r[3]};
        float4 o1 = {r[4], r[5], r[6], r[7]};
        ((float4*)out)[(size_t)row * 128 + lane * 2] = o0;
        ((float4*)out)[(size_t)row * 128 + lane * 2 + 1] = o1;
    }
}

// ------- shared GEMM core: (MT*32)x(NT*32) tile, BK=BKC, XOR-swizzled LDS -------
// r7 structure (single-buffer, 2 barriers/chunk; inter-block overlap hides drain).
// BKC=128 variant: two 64-col LDS planes per operand (each plane keeps the per-64-col
// XOR swizzle + contiguous gl16 dests); halves barrier count for K-heavy GEMMs.
template <int MT, int NT, int BKC>
__device__ __forceinline__ void gemm_core(const u16* __restrict__ A, const u16* __restrict__ Bt,
                                          int K, int m0, int n0, v4f (&acc)[MT][NT]) {
    constexpr int BM = MT * 32;
    constexpr int BN = NT * 32;
    constexpr int NH = BKC / 64;   // 64-col planes per chunk
    __shared__ u16 As[NH * BM * 64];
    __shared__ u16 Bs[NH * BN * 64];
    int tid = threadIdx.x;
    int w = tid >> 6, lane = tid & 63;
    int wr = (w >> 1) * (BM / 2), wc = (w & 1) * (BN / 2);
    int lr = lane & 15, lq = lane >> 4;
    int r8 = lane >> 3, cb = lane & 7;
    int scol = (cb ^ r8) * 8;

    v4f zero = {0.f, 0.f, 0.f, 0.f};
#pragma unroll
    for (int i = 0; i < MT; i++)
#pragma unroll
        for (int j = 0; j < NT; j++) acc[i][j] = zero;

    const u16* gA[MT]; u16* lA[MT];
#pragma unroll
    for (int j = 0; j < MT; j++) {
        int row0 = (MT * 8) * w + j * 8;
        gA[j] = A + (size_t)(m0 + row0 + r8) * K + scol;
        lA[j] = As + row0 * 64;
    }
    const u16* gB[NT]; u16* lB[NT];
#pragma unroll
    for (int j = 0; j < NT; j++) {
        int row0 = (NT * 8) * w + j * 8;
        gB[j] = Bt + (size_t)(n0 + row0 + r8) * K + scol;
        lB[j] = Bs + row0 * 64;
    }

    for (int k0 = 0; k0 < K; k0 += BKC) {
#pragma unroll
        for (int p = 0; p < NH; p++) {
#pragma unroll
            for (int j = 0; j < MT; j++) gl16(gA[j] + p * 64, lA[j] + p * (BM * 64));
#pragma unroll
            for (int j = 0; j < NT; j++) gl16(gB[j] + p * 64, lB[j] + p * (BN * 64));
        }
        __syncthreads();   // vmcnt drain -> tiles ready
#pragma unroll
        for (int kk = 0; kk < 2 * NH; kk++) {
            int pa = (kk >> 1) * (BM * 64);
            int pb = (kk >> 1) * (BN * 64);
            int xb = (((kk & 1) * 4 + lq) ^ (lr & 7)) * 8;
            v8bf af[MT], bfr[NT];
#pragma unroll
            for (int i = 0; i < MT; i++)
                af[i] = *(const v8bf*)&As[pa + (wr + i * 16 + lr) * 64 + xb];
#pragma unroll
            for (int j = 0; j < NT; j++)
                bfr[j] = *(const v8bf*)&Bs[pb + (wc + j * 16 + lr) * 64 + xb];
#pragma unroll
            for (int mt = 0; mt < MT; mt++)
#pragma unroll
                for (int nt = 0; nt < NT; nt++)
                    acc[mt][nt] = __builtin_amdgcn_mfma_f32_16x16x32_bf16(af[mt], bfr[nt], acc[mt][nt], 0, 0, 0);
        }
        __syncthreads();   // frag reads done before next DMA overwrites
#pragma unroll
        for (int j = 0; j < MT; j++) gA[j] += BKC;
#pragma unroll
        for (int j = 0; j < NT; j++) gB[j] += BKC;
    }
}

// ---- input projection: bf16 residual out + bias + sinusoid PE (N=512, 128x64, BK=128) ----
__global__ __launch_bounds__(256) void gemm_in_kernel(const u16* __restrict__ A,
                                                      const u16* __restrict__ Bt,
                                                      const float* __restrict__ bias,
                                                      u16* __restrict__ Out, int K) {
    int bx, by;
    swz_grid(8, bx, by);
    int n0 = bx * 64, m0 = by * 128;
    v4f acc[4][2];
    gemm_core<4, 2, 128>(A, Bt, K, m0, n0, acc);
    int tid = threadIdx.x, w = tid >> 6, lane = tid & 63;
    int lr = lane & 15, lq = lane >> 4;
    int wr = (w >> 1) * 64, wc = (w & 1) * 32;
#pragma unroll
    for (int mt = 0; mt < 4; mt++) {
#pragma unroll
        for (int nt = 0; nt < 2; nt++) {
            int col = n0 + wc + nt * 16 + lr;
            float bcol = bias[col];
            float freq = __builtin_amdgcn_exp2f((float)(col & ~1) * (-0.025953277f));
#pragma unroll
            for (int reg = 0; reg < 4; reg++) {
                int row = m0 + wr + mt * 16 + lq * 4 + reg;
                float rev = (float)(row & (S_LEN - 1)) * freq * 0.15915494309189535f;
                float fr = __builtin_amdgcn_fractf(rev);
                float pe = (col & 1) ? __builtin_amdgcn_cosf(fr) : __builtin_amdgcn_sinf(fr);
                Out[(size_t)row * DMODEL + col] = f2bf(acc[mt][nt][reg] + bcol + pe);
            }
        }
    }
}

// ---- fused QKV projection: N=1536 (128x128, BK=64); segment block-uniform ----
__global__ __launch_bounds__(256) void gemm_qkv_kernel(const u16* __restrict__ A,
                                                       const u16* __restrict__ Bt,
                                                       const float* __restrict__ bq,
                                                       const float* __restrict__ bk,
                                                       const float* __restrict__ bv,
                                                       u16* __restrict__ Qo,
                                                       u16* __restrict__ Ko,
                                                       u16* __restrict__ Vto, int K) {
    int bx, by;
    swz_grid(12, bx, by);
    int n0 = bx * 128, m0 = by * 128;
    v4f acc[4][4];
    gemm_core<4, 4, 64>(A, Bt, K, m0, n0, acc);
    int tid = threadIdx.x, w = tid >> 6, lane = tid & 63;
    int lr = lane & 15, lq = lane >> 4;
    int wr = (w >> 1) * 64, wc = (w & 1) * 64;
    int seg = n0 >> 9;
#pragma unroll
    for (int mt = 0; mt < 4; mt++) {
#pragma unroll
        for (int nt = 0; nt < 4; nt++) {
            int col = (n0 + wc + nt * 16 + lr) & (DMODEL - 1);
            if (seg == 0) {
                float bcol = bq[col];
#pragma unroll
                for (int reg = 0; reg < 4; reg++) {
                    int row = m0 + wr + mt * 16 + lq * 4 + reg;
                    Qo[(size_t)row * DMODEL + col] = f2bf((acc[mt][nt][reg] + bcol) * QSCALE);
                }
            } else if (seg == 1) {
                float bcol = bk[col];
#pragma unroll
                for (int reg = 0; reg < 4; reg++) {
                    int row = m0 + wr + mt * 16 + lq * 4 + reg;
                    Ko[(size_t)row * DMODEL + col] = f2bf(acc[mt][nt][reg] + bcol);
                }
            } else {
                float bcol = bv[col];
                int row0 = m0 + wr + mt * 16 + lq * 4;
                int bb = row0 >> 10, s0 = row0 & (S_LEN - 1);
                ushort4 o;
                o.x = f2bf(acc[mt][nt][0] + bcol);
                o.y = f2bf(acc[mt][nt][1] + bcol);
                o.z = f2bf(acc[mt][nt][2] + bcol);
                o.w = f2bf(acc[mt][nt][3] + bcol);
                *(ushort4*)(Vto + ((size_t)(bb * DMODEL + col)) * S_LEN + s0) = o;
            }
        }
    }
}

// ---- FFN1: bf16 out + bias + ReLU (N=2048, 128x128, BK=64) ----
__global__ __launch_bounds__(256) void gemm_relu_kernel(const u16* __restrict__ A,
                                                        const u16* __restrict__ Bt,
                                                        const float* __restrict__ bias,
                                                        u16* __restrict__ Out, int N, int K) {
    int bx, by;
    swz_grid(N >> 7, bx, by);
    int n0 = bx * 128, m0 = by * 128;
    v4f acc[4][4];
    gemm_core<4, 4, 64>(A, Bt, K, m0, n0, acc);
    int tid = threadIdx.x, w = tid >> 6, lane = tid & 63;
    int lr = lane & 15, lq = lane >> 4;
    int wr = (w >> 1) * 64, wc = (w & 1) * 64;
#pragma unroll
    for (int mt = 0; mt < 4; mt++) {
#pragma unroll
        for (int nt = 0; nt < 4; nt++) {
            int col = n0 + wc + nt * 16 + lr;
            float bcol = bias[col];
#pragma unroll
            for (int reg = 0; reg < 4; reg++) {
                int row = m0 + wr + mt * 16 + lq * 4 + reg;
                Out[(size_t)row * N + col] = f2bf(fmaxf(acc[mt][nt][reg] + bcol, 0.0f));
            }
        }
    }
}

// ---- O-proj / FFN2: bf16 residual RMW + bias (N=512, 128x64, BK=128) ----
__global__ __launch_bounds__(256) void gemm_res_kernel(const u16* __restrict__ A,
                                                       const u16* __restrict__ Bt,
                                                       const float* __restrict__ bias,
                                                       u16* __restrict__ Out, int K) {
    int bx, by;
    swz_grid(8, bx, by);
    int n0 = bx * 64, m0 = by * 128;
    v4f acc[4][2];
    gemm_core<4, 2, 128>(A, Bt, K, m0, n0, acc);
    int tid = threadIdx.x, w = tid >> 6, lane = tid & 63;
    int lr = lane & 15, lq = lane >> 4;
    int wr = (w >> 1) * 64, wc = (w & 1) * 32;
#pragma unroll
    for (int mt = 0; mt < 4; mt++) {
#pragma unroll
        for (int nt = 0; nt < 2; nt++) {
            int col = n0 + wc + nt * 16 + lr;
            float bcol = bias[col];
#pragma unroll
            for (int reg = 0; reg < 4; reg++) {
                int row = m0 + wr + mt * 16 + lq * 4 + reg;
                size_t idx = (size_t)row * DMODEL + col;
                Out[idx] = f2bf(bf2f(Out[idx]) + acc[mt][nt][reg] + bcol);
            }
        }
    }
}

// -------- MFMA flash attention v11: no split-K, in-register P, counted-vmcnt pipeline --------
__global__ __launch_bounds__(256, 4) void fattn_kernel(const u16* __restrict__ Qg,
                                                       const u16* __restrict__ Kg,
                                                       const u16* __restrict__ Vtg,
                                                       const float* __restrict__ rb,
                                                       const int* __restrict__ lengths,
                                                       u16* __restrict__ O) {
    int bid = blockIdx.x;
    int wg = (bid & 7) * 64 + (bid >> 3);
    int i = wg & 63;
    int h = wg >> 6;            // XCD-local head
    int b = i & 7;              // interleaved batch -> len-balanced CUs
    int qt = (i >> 3) & 7;
    int tid = threadIdx.x, w = tid >> 6, lane = tid & 63;
    int lr = lane & 15, lq = lane >> 4;
    __shared__ u16 Ks[3][64 * 64];
    __shared__ u16 Vs[3][64 * 64];
    __shared__ float rbs[128];
    int len = lengths[b];
    if (tid < 127) rbs[tid] = rb[h * 127 + tid] * 1.4426950408889634f;  // fold log2(e)

    int nchunks = (len + 63) >> 6;   // >= 8 (len >= 512)

    int qw = qt * 128 + w * 32;   // wave's 32 q rows
    v8bf qa[2][2];                // B-operand: rows q = qw + ntq*16 + lr
#pragma unroll
    for (int ntq = 0; ntq < 2; ntq++) {
        size_t qrow = ((size_t)(b * S_LEN + qw + ntq * 16 + lr)) * DMODEL + h * DK;
        qa[ntq][0] = *(const v8bf*)(Qg + qrow + lq * 8);
        qa[ntq][1] = *(const v8bf*)(Qg + qrow + 32 + lq * 8);
    }

    v4f zero = {0.f, 0.f, 0.f, 0.f};
    v4f Oacc[4][2];   // [dtile][ntq]: O^T -> lane holds q=lr col, d=dt*16+lq*4+r rows
#pragma unroll
    for (int dt = 0; dt < 4; dt++)
#pragma unroll
        for (int nt = 0; nt < 2; nt++) Oacc[dt][nt] = zero;
    float lsum[2] = {0.f, 0.f};

    const u16* Kbase = Kg + ((size_t)b * S_LEN) * DMODEL + h * DK;
    const u16* Vbase = Vtg + ((size_t)(b * DMODEL + h * DK)) * S_LEN;
    int r8 = lane >> 3, cb = lane & 7;
    int swz = (cb ^ r8) * 8;

    // prologue: DMA chunks 0,1 into buffers 0,1 (nchunks >= 8)
#pragma unroll
    for (int j = 0; j < 2; j++) {
        int row0 = w * 16 + j * 8;
        gl16(Kbase + (size_t)(row0 + r8) * DMODEL + swz, Ks[0] + row0 * 64);
        gl16(Vbase + (size_t)(row0 + r8) * S_LEN + swz, Vs[0] + row0 * 64);
    }
#pragma unroll
    for (int j = 0; j < 2; j++) {
        int row0 = w * 16 + j * 8;
        gl16(Kbase + (size_t)(64 + row0 + r8) * DMODEL + swz, Ks[1] + row0 * 64);
        gl16(Vbase + (size_t)(row0 + r8) * S_LEN + 64 + swz, Vs[1] + row0 * 64);
    }
    __syncthreads();   // one-time full drain: c0,c1 + rbs staged and visible

    u16 *KsA = Ks[0], *VsA = Vs[0];   // current compute buffer
    u16 *KsB = Ks[1], *VsB = Vs[1];   // next (in flight or landed)
    u16 *KsC = Ks[2], *VsC = Vs[2];   // landing slot for c(i+2)

    for (int ci = 0; ci < nchunks; ci++) {
        int kb0 = ci * 64;
        if (ci > 0) {
            if (ci + 1 < nchunks) asm volatile("s_waitcnt vmcnt(4)" ::: "memory");
            else                  asm volatile("s_waitcnt vmcnt(0)" ::: "memory");
            __builtin_amdgcn_s_barrier();        // all waves: buf A ready; compute c(ci-1) done
            __builtin_amdgcn_sched_barrier(0);   // pin issue below the barrier
        }
        if (ci + 2 < nchunks) {   // issue c(ci+2) into C (overwrites c(ci-1)'s buffer, now safe)
            int nk = kb0 + 128;
#pragma unroll
            for (int j = 0; j < 2; j++) {
                int row0 = w * 16 + j * 8;
                gl16(Kbase + (size_t)(nk + row0 + r8) * DMODEL + swz, KsC + row0 * 64);
                gl16(Vbase + (size_t)(row0 + r8) * S_LEN + nk + swz, VsC + row0 * 64);
            }
        }
        const u16* Ksc = KsA;
        const u16* Vsc = VsA;

        // S^T = K @ Q^T : lane holds key = kb0+mtk*16+lq*4+r (rows), q = qw+ntq*16+lr (cols)
        v4f S[4][2];
        __builtin_amdgcn_s_setprio(1);
#pragma unroll
        for (int mtk = 0; mtk < 4; mtk++) {
            int xb0 = (lq ^ (lr & 7)) * 8;
            int xb1 = ((4 + lq) ^ (lr & 7)) * 8;
            v8bf kf0 = *(const v8bf*)&Ksc[(mtk * 16 + lr) * 64 + xb0];
            v8bf kf1 = *(const v8bf*)&Ksc[(mtk * 16 + lr) * 64 + xb1];
#pragma unroll
            for (int ntq = 0; ntq < 2; ntq++) {
                v4f s = __builtin_amdgcn_mfma_f32_16x16x32_bf16(kf0, qa[ntq][0], zero, 0, 0, 0);
                S[mtk][ntq] = __builtin_amdgcn_mfma_f32_16x16x32_bf16(kf1, qa[ntq][1], s, 0, 0, 0);
            }
        }
        __builtin_amdgcn_s_setprio(0);

        bool edge = (kb0 + 64 > len);
        int dmin = qw - (kb0 + 63), dmax = qw + 31 - kb0;
        bool perel = !(dmax <= -63 || dmin >= 63);
        float bconst = (dmax <= -63) ? rbs[0] : rbs[126];
        uint2 pks[4][2];   // packed bf16 P, lane-local (keys lq*4+r of tile mtk, q col lr)
#pragma unroll
        for (int mtk = 0; mtk < 4; mtk++) {
#pragma unroll
            for (int ntq = 0; ntq < 2; ntq++) {
                int q = qw + ntq * 16 + lr;
                float p[4];
#pragma unroll
                for (int r = 0; r < 4; r++) {
                    int key = kb0 + mtk * 16 + lq * 4 + r;
                    float s = S[mtk][ntq][r];
                    if (perel) {
                        int d = q - key;
                        d = d < -63 ? -63 : (d > 63 ? 63 : d);
                        s += rbs[d + 63];
                    } else {
                        s += bconst;
                    }
                    float pv = __builtin_amdgcn_exp2f(s);
                    if (edge && key >= len) pv = 0.f;
                    lsum[ntq] += pv;
                    p[r] = pv;
                }
                // truncating bf16 pack: relative bias cancels in normalization
                pks[mtk][ntq].x = (__float_as_uint(p[1]) & 0xffff0000u) | (__float_as_uint(p[0]) >> 16);
                pks[mtk][ntq].y = (__float_as_uint(p[3]) & 0xffff0000u) | (__float_as_uint(p[2]) >> 16);
            }
        }

        // O^T += V^T @ P^T with permuted k-order: k=lq*8+j <-> key = kh*32 + (j<4 ? lq*4+j
        // : 16+lq*4+j-4). B-frag = lane's own pks; A-frag = two swizzled b64 reads from Vs.
        __builtin_amdgcn_s_setprio(1);
#pragma unroll
        for (int kh = 0; kh < 2; kh++) {
            uint4 tp0 = {pks[kh * 2][0].x, pks[kh * 2][0].y, pks[kh * 2 + 1][0].x, pks[kh * 2 + 1][0].y};
            uint4 tp1 = {pks[kh * 2][1].x, pks[kh * 2][1].y, pks[kh * 2 + 1][1].x, pks[kh * 2 + 1][1].y};
            v8bf pb0 = *(v8bf*)&tp0;
            v8bf pb1 = *(v8bf*)&tp1;
            int gl = kh * 4 + (lq >> 1);
            int sub = (lq & 1) * 4;
#pragma unroll
            for (int dt = 0; dt < 4; dt++) {
                int drow = (dt * 16 + lr) * 64;
                uint2 lo = *(const uint2*)&Vsc[drow + ((gl ^ (lr & 7)) * 8 + sub)];
                uint2 hi = *(const uint2*)&Vsc[drow + (((gl + 2) ^ (lr & 7)) * 8 + sub)];
                uint4 tv = {lo.x, lo.y, hi.x, hi.y};
                v8bf va = *(v8bf*)&tv;
                Oacc[dt][0] = __builtin_amdgcn_mfma_f32_16x16x32_bf16(va, pb0, Oacc[dt][0], 0, 0, 0);
                Oacc[dt][1] = __builtin_amdgcn_mfma_f32_16x16x32_bf16(va, pb1, Oacc[dt][1], 0, 0, 0);
            }
        }
        __builtin_amdgcn_s_setprio(0);

        // rotate buffers: A <- B <- C <- A
        u16* t;
        t = KsA; KsA = KsB; KsB = KsC; KsC = t;
        t = VsA; VsA = VsB; VsB = VsC; VsC = t;
    }

    // reduce row sums across key quads (lane then holds total for q = qw+ntq*16+lr)
    float inv[2];
#pragma unroll
    for (int ntq = 0; ntq < 2; ntq++) {
        float s = lsum[ntq];
        s += __shfl_xor(s, 16);
        s += __shfl_xor(s, 32);
        inv[ntq] = 1.0f / s;
    }
    // normalized O (bf16): lane writes 4 consecutive d per tile -> 8B stores
#pragma unroll
    for (int dt = 0; dt < 4; dt++) {
#pragma unroll
        for (int ntq = 0; ntq < 2; ntq++) {
            size_t off = (size_t)(b * S_LEN + qw + ntq * 16 + lr) * DMODEL + h * DK + dt * 16 + lq * 4;
            ushort4 o;
            o.x = f2bf(Oacc[dt][ntq][0] * inv[ntq]);
            o.y = f2bf(Oacc[dt][ntq][1] * inv[ntq]);
            o.z = f2bf(Oacc[dt][ntq][2] * inv[ntq]);
            o.w = f2bf(Oacc[dt][ntq][3] * inv[ntq]);
            *(ushort4*)(O + off) = o;
        }
    }
}

extern "C" void kernel_launch(void* const* d_in, const int* in_sizes, int n_in,
                              void* d_out, int out_size, void* d_ws, size_t ws_size,
                              hipStream_t stream) {
    const float* inputs   = (const float*)d_in[0];
    const int*   lengths  = (const int*)d_in[1];
    const float* W_in     = (const float*)d_in[2];
    const float* b_in     = (const float*)d_in[3];
    const float* Wq       = (const float*)d_in[4];
    const float* bq       = (const float*)d_in[5];
    const float* Wk       = (const float*)d_in[6];
    const float* bk       = (const float*)d_in[7];
    const float* Wv       = (const float*)d_in[8];
    const float* bv       = (const float*)d_in[9];
    const float* Wo       = (const float*)d_in[10];
    const float* bo       = (const float*)d_in[11];
    const float* rel_bias = (const float*)d_in[12];
    const float* W1       = (const float*)d_in[13];
    const float* b1       = (const float*)d_in[14];
    const float* W2       = (const float*)d_in[15];
    const float* b2       = (const float*)d_in[16];
    const float* g1       = (const float*)d_in[17];
    const float* be1      = (const float*)d_in[18];
    const float* g2       = (const float*)d_in[19];
    const float* be2      = (const float*)d_in[20];
    const float* gf       = (const float*)d_in[21];
    const float* bef      = (const float*)d_in[22];

    // ---- workspace layout (tight, liveness-based unions; total ≈ 63 MB) ----
    char* ws = (char*)d_ws;
    u16* xbuf   = (u16*)ws;            ws += (size_t)MROWS * DMODEL * 2;   // 8.39MB residual bf16
    u16* hbuf   = (u16*)ws;            ws += (size_t)MROWS * DMODEL * 2;   // 8.39MB LN-out / attn-out
    u16* aobuf  = hbuf;                                                    // alias (time-shared)
    u16* qbf    = (u16*)ws;            ws += (size_t)MROWS * FF_DIM * 2;   // 32MB union region
    u16* kbf    = qbf + (size_t)MROWS * DMODEL;
    u16* vtbf   = kbf + (size_t)MROWS * DMODEL;
    u16* tbuf   = qbf;                 // FFN mid (32MB) reuses q/k/vt region
    u16* inbf   = qbf;                 // bf16 inputs (4.2MB), dead before qkv writes
    u16* wt_in  = (u16*)ws;            ws += (size_t)DMODEL * IN_DIM * 2;
    u16 *qkvw[2], *wto[2], *wt1[2], *wt2[2];
    for (int l = 0; l < 2; l++) { qkvw[l] = (u16*)ws; ws += (size_t)3 * DMODEL * DMODEL * 2; }
    for (int l = 0; l < 2; l++) { wto[l] = (u16*)ws; ws += (size_t)DMODEL * DMODEL * 2; }
    for (int l = 0; l < 2; l++) { wt1[l] = (u16*)ws; ws += (size_t)FF_DIM * DMODEL * 2; }
    for (int l = 0; l < 2; l++) { wt2[l] = (u16*)ws; ws += (size_t)DMODEL * FF_DIM * 2; }

    TArgs ta;
    int ti = 0, acct = 0;
    auto add = [&](const float* s, u16* d, int K, int N) {
        ta.d[ti] = {s, d, K, N};
        ta.start[ti] = acct;
        int tn = N / 32;
        int l2 = 31 - __builtin_clz((unsigned)tn);
        ta.l2tn[ti] = l2;
        acct += (K / 32) * tn;
        ti++;
    };
    add(W_in, wt_in, IN_DIM, DMODEL);
    for (int l = 0; l < 2; l++) {
        add(Wq + (size_t)l * DMODEL * DMODEL, qkvw[l], DMODEL, DMODEL);
        add(Wk + (size_t)l * DMODEL * DMODEL, qkvw[l] + (size_t)DMODEL * DMODEL, DMODEL, DMODEL);
        add(Wv + (size_t)l * DMODEL * DMODEL, qkvw[l] + (size_t)2 * DMODEL * DMODEL, DMODEL, DMODEL);
        add(Wo + (size_t)l * DMODEL * DMODEL, wto[l], DMODEL, DMODEL);
        add(W1 + (size_t)l * DMODEL * FF_DIM, wt1[l], DMODEL, FF_DIM);
        add(W2 + (size_t)l * FF_DIM * DMODEL, wt2[l], FF_DIM, DMODEL);
    }
    ta.start[13] = acct;

    conv_bf16_kernel<<<dim3((MROWS * IN_DIM / 4 + 255) / 256), 256, 0, stream>>>(
        inputs, inbf, MROWS * IN_DIM / 4);
    transpose_conv_kernel<<<dim3(acct), dim3(32, 8), 0, stream>>>(ta);

    gemm_in_kernel<<<dim3(512), 256, 0, stream>>>(
        inbf, wt_in, b_in, xbuf, IN_DIM);

    for (int l = 0; l < 2; l++) {
        ln_kernel<true><<<MROWS / 4, 256, 0, stream>>>(xbuf, g1 + l * DMODEL, be1 + l * DMODEL, hbuf);
        gemm_qkv_kernel<<<dim3(768), 256, 0, stream>>>(
            hbuf, qkvw[l], bq + l * DMODEL, bk + l * DMODEL, bv + l * DMODEL,
            qbf, kbf, vtbf, DMODEL);
        fattn_kernel<<<dim3(512), 256, 0, stream>>>(
            qbf, kbf, vtbf, rel_bias + (size_t)l * NHEAD * 127, lengths, aobuf);
        gemm_res_kernel<<<dim3(512), 256, 0, stream>>>(
            aobuf, wto[l], bo + l * DMODEL, xbuf, DMODEL);
        ln_kernel<true><<<MROWS / 4, 256, 0, stream>>>(xbuf, g2 + l * DMODEL, be2 + l * DMODEL, hbuf);
        gemm_relu_kernel<<<dim3(1024), 256, 0, stream>>>(
            hbuf, wt1[l], b1 + l * FF_DIM, tbuf, FF_DIM, DMODEL);
        gemm_res_kernel<<<dim3(512), 256, 0, stream>>>(
            tbuf, wt2[l], b2 + l * DMODEL, xbuf, FF_DIM);
    }
    ln_kernel<false><<<MROWS / 4, 256, 0, stream>>>(xbuf, gf, bef, d_out);
}